// Round 7
// baseline (27760.205 us; speedup 1.0000x reference)
//
#include <hip/hip_runtime.h>
#include <cstdint>
#include <cstddef>

// 4-layer projected LSTM. B=64 T=256 D=512 H=1024 P=256. fp32 in/out.
// Split-bf16 (hi+lo) MFMA operands, 3 MFMAs per product (absmax ~6e-5).
//
// Round-13: round-12 LAYER-WAVEFRONT kernel + silent-launch hardening.
//   Diagnosis: rounds 8/9/12 (three different kernels) all returned absmax
//   == 2.319336e-02 == max|ref| exactly -> out never written. Identical
//   output from different programs => the kernels never ran. We swallow
//   hipLaunchCooperativeKernel's status; coop launch validates occupancy/
//   capacity before enqueue, normal launch does not.
//   Fix: check the coop-launch status and FALL BACK to hipLaunchKernelGGL.
//   (Hand-rolled barrier needs only co-residency: 128 WGs on 256 CUs.)
//   Also: phase-1 unroll 4->2 (halve in-flight VGPR pressure).
//
// Structure (from round-12): 4 layer groups x 32 WGs run CONCURRENTLY;
// group l processes t = tick - l. 259 ticks x 2 phases = 518 barriers
// (vs 2048 in the round-7 lineage whose 11.5us/phase floor = whole runtime).
// Deps via depth-2 y rings + per-layer h buffer, ALL cross-WG traffic
// agent-scope (no cached staleness anywhere). Weights read from global f32
// and split on the fly (WG-private rows => L2-resident).
// Workspace: [cnt 4K][hR 4x256K][yR 8x64K] ~= 1.55 MB. LDS 16.5 KB.

#define B_ 64
#define T_ 256
#define D_ 512
#define H_ 1024
#define P_ 256
#define NWG 128
#define NTHR 128

using short8  = __attribute__((ext_vector_type(8))) short;
using f32x16  = __attribute__((ext_vector_type(16))) float;
using f32x4   = __attribute__((ext_vector_type(4))) float;

__device__ inline float bf2f(short s) {
  unsigned u = ((unsigned)(unsigned short)s) << 16;
  return __builtin_bit_cast(float, u);
}
__device__ inline unsigned short f2bf(float f) {
  unsigned u = __builtin_bit_cast(unsigned, f);
  u += 0x7fffu + ((u >> 16) & 1u);   // RTNE
  return (unsigned short)(u >> 16);
}
__device__ inline void split1(float v, short& hi, short& lo) {
  unsigned short h = f2bf(v);
  hi = (short)h;
  lo = (short)f2bf(v - bf2f((short)h));
}
__device__ inline unsigned packf(float v) {
  short h, l;
  split1(v, h, l);
  return (unsigned)(unsigned short)h | ((unsigned)(unsigned short)l << 16);
}
__device__ inline void split8(const float* p, short8& hi, short8& lo) {
  float4 a = *(const float4*)p;
  float4 b = *(const float4*)(p + 4);
  float v[8] = {a.x, a.y, a.z, a.w, b.x, b.y, b.z, b.w};
#pragma unroll
  for (int i = 0; i < 8; ++i) {
    short h, l;
    split1(v[i], h, l);
    hi[i] = h; lo[i] = l;
  }
}
// 8 packed elems via agent-coherent loads (cross-WG h / y traffic)
__device__ inline void unpack_a8(const unsigned* p, short8& hi, short8& lo) {
#pragma unroll
  for (int i = 0; i < 4; ++i) {
    unsigned long long v = __hip_atomic_load((const unsigned long long*)p + i,
                                             __ATOMIC_RELAXED, __HIP_MEMORY_SCOPE_AGENT);
    unsigned w0 = (unsigned)v, w1 = (unsigned)(v >> 32);
    hi[2 * i]     = (short)(w0 & 0xffff);
    lo[2 * i]     = (short)(w0 >> 16);
    hi[2 * i + 1] = (short)(w1 & 0xffff);
    lo[2 * i + 1] = (short)(w1 >> 16);
  }
}
__device__ inline float sigm(float x)   { return 1.f / (1.f + __expf(-x)); }
__device__ inline float tanh_f(float x) { return 1.f - 2.f / (__expf(2.f * x) + 1.f); }

// Round-7 verified grid barrier: striped RMW arrivals (32 counters, 64B
// apart, 4 arrivals each), WG0 wave-parallel scan + release word, others
// poll one line. ep increases by exactly 1 per call, starting at 1.
#define NCNT 32
#define REL_IDX 768   // u32 index of release word (byte 3072, own line)
__device__ inline void gbar(unsigned* cnt, unsigned ep) {
  __syncthreads();   // compiler drains vmcnt before s_barrier: stores visible
  if (blockIdx.x == 0) {
    if (threadIdx.x < 64) {                // wave 0 scans in parallel
      if (threadIdx.x == 0)
        __hip_atomic_fetch_add(&cnt[0], 1u, __ATOMIC_RELAXED,
                               __HIP_MEMORY_SCOPE_AGENT);
      const unsigned tgt = ep * (NWG / NCNT);
      for (;;) {
        unsigned v = tgt;                  // lanes 32..63: trivially done
        if (threadIdx.x < NCNT)
          v = __hip_atomic_load(&cnt[threadIdx.x * 16], __ATOMIC_RELAXED,
                                __HIP_MEMORY_SCOPE_AGENT);
        if (__all(v >= tgt)) break;
        __builtin_amdgcn_s_sleep(2);
      }
      if (threadIdx.x == 0)
        __hip_atomic_store(&cnt[REL_IDX], ep, __ATOMIC_RELAXED,
                           __HIP_MEMORY_SCOPE_AGENT);
    }
  } else {
    if (threadIdx.x == 0) {
      __hip_atomic_fetch_add(&cnt[(blockIdx.x & (NCNT - 1)) * 16], 1u,
                             __ATOMIC_RELAXED, __HIP_MEMORY_SCOPE_AGENT);
      while (__hip_atomic_load(&cnt[REL_IDX], __ATOMIC_RELAXED,
                               __HIP_MEMORY_SCOPE_AGENT) < ep)
        __builtin_amdgcn_s_sleep(2);
    }
  }
  __syncthreads();
}

__global__ __launch_bounds__(NTHR) void lstm_kernel(
    const float* __restrict__ x,
    const float* __restrict__ Wih0, const float* __restrict__ Whh0,
    const float* __restrict__ bih0, const float* __restrict__ bhh0,
    const float* __restrict__ Whr0,
    const float* __restrict__ Wihs, const float* __restrict__ Whhs,
    const float* __restrict__ bihs, const float* __restrict__ bhhs,
    const float* __restrict__ Whrs,
    float* __restrict__ out,
    unsigned* __restrict__ yR, unsigned* __restrict__ hR,
    unsigned* __restrict__ cnt)
{
  __shared__ float sG[64 * 64];     // 16 KB (one 2-tile pass of gates)
  __shared__ float sBias[128];      // 512 B

  const int tid  = threadIdx.x;
  const int wg   = blockIdx.x;
  const int lane = tid & 63;
  const int wave = tid >> 6;
  const int lg   = wg >> 5;         // layer this WG serves (0..3)
  const int wgl  = wg & 31;         // index within layer group

  // mfma_f32_32x32x16_bf16 lane geometry:
  //   A[m][k]: m = lane&31 (+ wave*32), k = (lane>>5)*8 + j
  //   B[k][n] = W[n][k]: n = lane&31
  //   D: col = lane&31, row = (reg&3) + 8*(reg>>2) + 4*(lane>>5)
  const int m1  = wave * 32 + (lane & 31);  // batch row
  const int n1  = lane & 31;                // local gate row (within tile)
  const int kh1 = (lane >> 5) * 8;

  // per-layer weights/biases
  const float* Wih = (lg == 0) ? Wih0 : Wihs + (size_t)(lg - 1) * 4096 * 256;
  const float* Whh = (lg == 0) ? Whh0 : Whhs + (size_t)(lg - 1) * 4096 * 256;
  const float* bih = (lg == 0) ? bih0 : bihs + (size_t)(lg - 1) * 4096;
  const float* bhh = (lg == 0) ? bhh0 : bhhs + (size_t)(lg - 1) * 4096;
  const float* Whr = (lg == 0) ? Whr0 : Whrs + (size_t)(lg - 1) * 256 * 1024;

  unsigned* hP = hR + (size_t)lg * (B_ * H_);   // this layer's h (packed u32)

  // bias staging (once; WG's layer is fixed). col c = p*64+q*32+j*4+g,
  // unit = wgl*32 + p*16 + q*8 + j, row R = g*H + unit.
  {
    int c = tid;
    int p = c >> 6, q = (c >> 5) & 1, j = (c >> 2) & 7, g = c & 3;
    int unit = wgl * 32 + p * 16 + q * 8 + j;
    int R = g * H_ + unit;
    sBias[c] = bih[R] + bhh[R];
  }
  __syncthreads();

  float cs[16];                     // cell state: 64 batch x 32 units / 128thr
#pragma unroll
  for (int i = 0; i < 16; ++i) cs[i] = 0.f;

  unsigned ep = 0;

  for (int tick = 0; tick < T_ + 3; ++tick) {
    const int t = tick - lg;
    const bool act = (t >= 0) && (t < T_);

    // ================= phase 1: gates + state update =================
    if (act) {
#pragma unroll
      for (int p = 0; p < 2; ++p) {          // 2 passes x 2 n-tiles
        const int R0 = (n1 & 3) * H_ + wgl * 32 + p * 16 + (n1 >> 2);
        const int R1 = R0 + 8;
        f32x16 a0h = {}, a0l = {}, a0m = {};
        f32x16 a1h = {}, a1l = {}, a1m = {};

        // ---- input term ----
        if (lg == 0) {
          const float* ax = x + ((size_t)m1 * T_ + t) * D_ + kh1;
          const float* b0 = Wih + (size_t)R0 * D_ + kh1;
          const float* b1 = Wih + (size_t)R1 * D_ + kh1;
#pragma unroll 2
          for (int k0 = 0; k0 < D_; k0 += 16) {
            short8 Ah, Al, B0h, B0l, B1h, B1l;
            split8(ax + k0, Ah, Al);
            split8(b0 + k0, B0h, B0l);
            split8(b1 + k0, B1h, B1l);
            a0h = __builtin_amdgcn_mfma_f32_32x32x16_bf16(Ah, B0h, a0h, 0, 0, 0);
            a0l = __builtin_amdgcn_mfma_f32_32x32x16_bf16(Ah, B0l, a0l, 0, 0, 0);
            a0m = __builtin_amdgcn_mfma_f32_32x32x16_bf16(Al, B0h, a0m, 0, 0, 0);
            a1h = __builtin_amdgcn_mfma_f32_32x32x16_bf16(Ah, B1h, a1h, 0, 0, 0);
            a1l = __builtin_amdgcn_mfma_f32_32x32x16_bf16(Ah, B1l, a1l, 0, 0, 0);
            a1m = __builtin_amdgcn_mfma_f32_32x32x16_bf16(Al, B1h, a1m, 0, 0, 0);
          }
        } else {
          const unsigned* ay = yR + ((size_t)((lg - 1) * 2 + (t & 1)) * (B_ * P_))
                               + (size_t)m1 * P_ + kh1;
          const float* b0 = Wih + (size_t)R0 * P_ + kh1;
          const float* b1 = Wih + (size_t)R1 * P_ + kh1;
#pragma unroll 2
          for (int k0 = 0; k0 < P_; k0 += 16) {
            short8 Ah, Al, B0h, B0l, B1h, B1l;
            unpack_a8(ay + k0, Ah, Al);
            split8(b0 + k0, B0h, B0l);
            split8(b1 + k0, B1h, B1l);
            a0h = __builtin_amdgcn_mfma_f32_32x32x16_bf16(Ah, B0h, a0h, 0, 0, 0);
            a0l = __builtin_amdgcn_mfma_f32_32x32x16_bf16(Ah, B0l, a0l, 0, 0, 0);
            a0m = __builtin_amdgcn_mfma_f32_32x32x16_bf16(Al, B0h, a0m, 0, 0, 0);
            a1h = __builtin_amdgcn_mfma_f32_32x32x16_bf16(Ah, B1h, a1h, 0, 0, 0);
            a1l = __builtin_amdgcn_mfma_f32_32x32x16_bf16(Ah, B1l, a1l, 0, 0, 0);
            a1m = __builtin_amdgcn_mfma_f32_32x32x16_bf16(Al, B1h, a1m, 0, 0, 0);
          }
        }
        // ---- recurrent term y_l(t-1) ----
        if (t > 0) {
          const unsigned* ay = yR + ((size_t)(lg * 2 + ((t - 1) & 1)) * (B_ * P_))
                               + (size_t)m1 * P_ + kh1;
          const float* b0 = Whh + (size_t)R0 * P_ + kh1;
          const float* b1 = Whh + (size_t)R1 * P_ + kh1;
#pragma unroll 2
          for (int k0 = 0; k0 < P_; k0 += 16) {
            short8 Ah, Al, B0h, B0l, B1h, B1l;
            unpack_a8(ay + k0, Ah, Al);
            split8(b0 + k0, B0h, B0l);
            split8(b1 + k0, B1h, B1l);
            a0h = __builtin_amdgcn_mfma_f32_32x32x16_bf16(Ah, B0h, a0h, 0, 0, 0);
            a0l = __builtin_amdgcn_mfma_f32_32x32x16_bf16(Ah, B0l, a0l, 0, 0, 0);
            a0m = __builtin_amdgcn_mfma_f32_32x32x16_bf16(Al, B0h, a0m, 0, 0, 0);
            a1h = __builtin_amdgcn_mfma_f32_32x32x16_bf16(Ah, B1h, a1h, 0, 0, 0);
            a1l = __builtin_amdgcn_mfma_f32_32x32x16_bf16(Ah, B1l, a1l, 0, 0, 0);
            a1m = __builtin_amdgcn_mfma_f32_32x32x16_bf16(Al, B1h, a1m, 0, 0, 0);
          }
        }
        // ---- writeback both tiles ----
#pragma unroll
        for (int r = 0; r < 16; ++r) {
          int mrow = (r & 3) + 8 * (r >> 2) + 4 * (lane >> 5) + wave * 32;
          sG[mrow * 64 + n1]      = a0h[r] + a0l[r] + a0m[r];
          sG[mrow * 64 + 32 + n1] = a1h[r] + a1l[r] + a1m[r];
        }
        __syncthreads();
        // ---- elementwise for this pass (16 units; 8 per thread) ----
        {
          const int b = tid >> 1, q = tid & 1;
          const float* gp = &sG[b * 64 + q * 32];
          const float* bp = &sBias[p * 64 + q * 32];
          unsigned pw[8];
#pragma unroll
          for (int j = 0; j < 8; ++j) {
            float ii = sigm(gp[j * 4 + 0] + bp[j * 4 + 0]);
            float ff = sigm(gp[j * 4 + 1] + bp[j * 4 + 1]);
            float gg = tanh_f(gp[j * 4 + 2] + bp[j * 4 + 2]);
            float oo = sigm(gp[j * 4 + 3] + bp[j * 4 + 3]);
            float cv = ff * cs[p * 8 + j] + ii * gg;
            cs[p * 8 + j] = cv;
            pw[j] = packf(oo * tanh_f(cv));
          }
          size_t ho = (size_t)b * H_ + wgl * 32 + p * 16 + q * 8;
#pragma unroll
          for (int j = 0; j < 4; ++j) {
            unsigned long long qq = (unsigned long long)pw[2 * j] |
                                    ((unsigned long long)pw[2 * j + 1] << 32);
            __hip_atomic_store((unsigned long long*)&hP[ho + 2 * j], qq,
                               __ATOMIC_RELAXED, __HIP_MEMORY_SCOPE_AGENT);
          }
        }
        __syncthreads();   // sG reused by next pass
      }
    }
    ep++; gbar(cnt, ep);

    // ================= phase 2: projection y_t = h @ Whr^T ===========
    // 64 waves in the group, 1 16x16 tile each, full K=1024.
    // mfma_f32_16x16x32_bf16: A m=lane&15, k=(lane>>4)*8+j; B n=lane&15;
    // D col=lane&15, row=(lane>>4)*4+reg.
    if (act) {
      const int tile = wgl * 2 + wave;          // 0..63
      const int mt0  = (tile >> 4) * 16;        // batch block
      const int p0   = (tile & 15) * 16;        // proj-col block
      const int l16  = lane & 15;
      const int kh2  = (lane >> 4) * 8;
      const unsigned* ahp = hP + (size_t)(mt0 + l16) * H_ + kh2;
      const float*    bwf = Whr + (size_t)(p0 + l16) * H_ + kh2;
      f32x4 q0 = {}, q1 = {}, q2 = {};
#pragma unroll 4
      for (int k0 = 0; k0 < H_; k0 += 32) {
        short8 Ah, Al, Bh, Bl;
        unpack_a8(ahp + k0, Ah, Al);
        split8(bwf + k0, Bh, Bl);
        q0 = __builtin_amdgcn_mfma_f32_16x16x32_bf16(Ah, Bh, q0, 0, 0, 0);
        q1 = __builtin_amdgcn_mfma_f32_16x16x32_bf16(Ah, Bl, q1, 0, 0, 0);
        q2 = __builtin_amdgcn_mfma_f32_16x16x32_bf16(Al, Bh, q2, 0, 0, 0);
      }
      unsigned* yo = yR + ((size_t)(lg * 2 + (t & 1)) * (B_ * P_));
#pragma unroll
      for (int r = 0; r < 4; ++r) {
        int mm = mt0 + (lane >> 4) * 4 + r;
        float v = q0[r] + q1[r] + q2[r];
        __hip_atomic_store(&yo[(size_t)mm * P_ + p0 + l16], packf(v),
                           __ATOMIC_RELAXED, __HIP_MEMORY_SCOPE_AGENT);
        if (lg == 3 && t == T_ - 1) out[mm * P_ + p0 + l16] = v;
      }
    }
    ep++; gbar(cnt, ep);
  }
}

extern "C" void kernel_launch(void* const* d_in, const int* in_sizes, int n_in,
                              void* d_out, int out_size, void* d_ws, size_t ws_size,
                              hipStream_t stream) {
  const float* x    = (const float*)d_in[0];
  const float* Wih0 = (const float*)d_in[1];
  const float* Whh0 = (const float*)d_in[2];
  const float* bih0 = (const float*)d_in[3];
  const float* bhh0 = (const float*)d_in[4];
  const float* Whr0 = (const float*)d_in[5];
  const float* Wihs = (const float*)d_in[6];
  const float* Whhs = (const float*)d_in[7];
  const float* bihs = (const float*)d_in[8];
  const float* bhhs = (const float*)d_in[9];
  const float* Whrs = (const float*)d_in[10];
  float* out = (float*)d_out;

  char* ws = (char*)d_ws;
  unsigned* cnt = (unsigned*)ws;                          // 4 KB
  unsigned* hR  = (unsigned*)(ws + 4096);                 // 4 x 256 KB
  unsigned* yR  = (unsigned*)(ws + 4096 + 1048576);       // 8 x 64 KB
  // total ~1.55 MB

  (void)hipMemsetAsync(d_ws, 0, 4096, stream);   // zero barrier counters

  void* args[] = {&x, &Wih0, &Whh0, &bih0, &bhh0, &Whr0,
                  &Wihs, &Whhs, &bihs, &bhhs, &Whrs,
                  &out, &yR, &hR, &cnt};
  hipError_t st = hipLaunchCooperativeKernel((void*)lstm_kernel, dim3(NWG),
                                             dim3(NTHR), args, 0, stream);
  if (st != hipSuccess) {
    // Silent coop-launch rejection observed (out never written). Our grid
    // barrier is hand-rolled; 128 WGs on 256 CUs are co-resident under a
    // normal launch too.
    hipLaunchKernelGGL(lstm_kernel, dim3(NWG), dim3(NTHR), 0, stream,
                       x, Wih0, Whh0, bih0, bhh0, Whr0,
                       Wihs, Whhs, bihs, bhhs, Whrs,
                       out, yR, hR, cnt);
  }
}

// Round 8
// 21381.390 us; speedup vs baseline: 1.2983x; 1.2983x over previous
//
#include <hip/hip_runtime.h>
#include <cstdint>
#include <cstddef>

// 4-layer projected LSTM. B=64 T=256 D=512 H=1024 P=256. fp32 in/out.
// Split-bf16 (hi+lo) MFMA operands, 3 MFMAs per product (absmax ~6e-5).
//
// Round-14 (round-13 PASSED at 27.6ms -> launch-fallback diagnosis confirmed;
// counters: 53us/tick, ~45us of it exposed memory latency in the 64-stage
// serial k-chain; FETCH 6.7GB = weight streaming, 290GB/s latency-limited):
//  1. MERGED phase-1: all 4 n-tiles per k-iter (12 MFMA chains, ~192 acc
//     regs -- occupancy irrelevant at 1 WG/CU). A(y) loaded ONCE not twice;
//     A-atomic chain 64 -> 32 stages; 12 MFMAs + 4 B-loads of independent
//     work per stage to hide the next A-load.
//  2. PACKED pre-split weights (hi|lo u32, 40MB workspace, one-time
//     prologue; template<PK> fallback = exact round-13 f32 path if ws too
//     small). Kills the split8 VALU chain in front of every MFMA.
//  3. Phase-2: two interleaved K-halves (6 chains) -> h-chain 32 -> 16
//     stages; packed Whr.
//  Launch: coop with status check + normal-launch fallback (round-13 fix).
// Workspace: [cnt 4K][hR 1M][yR 512K][WP 40M] ~= 41.5 MB (fallback: 1.55 MB).

#define B_ 64
#define T_ 256
#define D_ 512
#define H_ 1024
#define P_ 256
#define NWG 128
#define NTHR 128

using short8  = __attribute__((ext_vector_type(8))) short;
using f32x16  = __attribute__((ext_vector_type(16))) float;
using f32x4   = __attribute__((ext_vector_type(4))) float;

__device__ inline float bf2f(short s) {
  unsigned u = ((unsigned)(unsigned short)s) << 16;
  return __builtin_bit_cast(float, u);
}
__device__ inline unsigned short f2bf(float f) {
  unsigned u = __builtin_bit_cast(unsigned, f);
  u += 0x7fffu + ((u >> 16) & 1u);   // RTNE
  return (unsigned short)(u >> 16);
}
__device__ inline void split1(float v, short& hi, short& lo) {
  unsigned short h = f2bf(v);
  hi = (short)h;
  lo = (short)f2bf(v - bf2f((short)h));
}
__device__ inline unsigned packf(float v) {
  short h, l;
  split1(v, h, l);
  return (unsigned)(unsigned short)h | ((unsigned)(unsigned short)l << 16);
}
__device__ inline void split8(const float* p, short8& hi, short8& lo) {
  float4 a = *(const float4*)p;
  float4 b = *(const float4*)(p + 4);
  float v[8] = {a.x, a.y, a.z, a.w, b.x, b.y, b.z, b.w};
#pragma unroll
  for (int i = 0; i < 8; ++i) {
    short h, l;
    split1(v[i], h, l);
    hi[i] = h; lo[i] = l;
  }
}
// 8 packed elems via normal cached loads (pre-split weights)
__device__ inline void unpack_c8(const unsigned* p, short8& hi, short8& lo) {
  uint4 a = *(const uint4*)p;
  uint4 b = *(const uint4*)(p + 4);
  unsigned w[8] = {a.x, a.y, a.z, a.w, b.x, b.y, b.z, b.w};
#pragma unroll
  for (int i = 0; i < 8; ++i) {
    hi[i] = (short)(w[i] & 0xffff);
    lo[i] = (short)(w[i] >> 16);
  }
}
// 8 packed elems via agent-coherent loads (cross-WG h / y traffic)
__device__ inline void unpack_a8(const unsigned* p, short8& hi, short8& lo) {
#pragma unroll
  for (int i = 0; i < 4; ++i) {
    unsigned long long v = __hip_atomic_load((const unsigned long long*)p + i,
                                             __ATOMIC_RELAXED, __HIP_MEMORY_SCOPE_AGENT);
    unsigned w0 = (unsigned)v, w1 = (unsigned)(v >> 32);
    hi[2 * i]     = (short)(w0 & 0xffff);
    lo[2 * i]     = (short)(w0 >> 16);
    hi[2 * i + 1] = (short)(w1 & 0xffff);
    lo[2 * i + 1] = (short)(w1 >> 16);
  }
}
__device__ inline float sigm(float x)   { return 1.f / (1.f + __expf(-x)); }
__device__ inline float tanh_f(float x) { return 1.f - 2.f / (__expf(2.f * x) + 1.f); }

// Round-7 verified grid barrier. ep increases by exactly 1 per call.
#define NCNT 32
#define REL_IDX 768   // u32 index of release word (byte 3072, own line)
__device__ inline void gbar(unsigned* cnt, unsigned ep) {
  __syncthreads();   // compiler drains vmcnt before s_barrier: stores visible
  if (blockIdx.x == 0) {
    if (threadIdx.x < 64) {                // wave 0 scans in parallel
      if (threadIdx.x == 0)
        __hip_atomic_fetch_add(&cnt[0], 1u, __ATOMIC_RELAXED,
                               __HIP_MEMORY_SCOPE_AGENT);
      const unsigned tgt = ep * (NWG / NCNT);
      for (;;) {
        unsigned v = tgt;                  // lanes 32..63: trivially done
        if (threadIdx.x < NCNT)
          v = __hip_atomic_load(&cnt[threadIdx.x * 16], __ATOMIC_RELAXED,
                                __HIP_MEMORY_SCOPE_AGENT);
        if (__all(v >= tgt)) break;
        __builtin_amdgcn_s_sleep(2);
      }
      if (threadIdx.x == 0)
        __hip_atomic_store(&cnt[REL_IDX], ep, __ATOMIC_RELAXED,
                           __HIP_MEMORY_SCOPE_AGENT);
    }
  } else {
    if (threadIdx.x == 0) {
      __hip_atomic_fetch_add(&cnt[(blockIdx.x & (NCNT - 1)) * 16], 1u,
                             __ATOMIC_RELAXED, __HIP_MEMORY_SCOPE_AGENT);
      while (__hip_atomic_load(&cnt[REL_IDX], __ATOMIC_RELAXED,
                               __HIP_MEMORY_SCOPE_AGENT) < ep)
        __builtin_amdgcn_s_sleep(2);
    }
  }
  __syncthreads();
}

// packed-weight region offsets (u32 units): [W0I 2097152][W0H 1048576]
// [WIs 3x1048576][WHs 3x1048576][WR 4x262144] = 10485760 u32 = 40 MB.
#define WP_W0I 0
#define WP_W0H 2097152
#define WP_WIS 3145728
#define WP_WHS 6291456
#define WP_WR  9437184
#define WP_CHUNKS 1310720   // total 8-elem chunks

template <bool PK>
__global__ __launch_bounds__(NTHR) void lstm_kernel(
    const float* __restrict__ x,
    const float* __restrict__ Wih0, const float* __restrict__ Whh0,
    const float* __restrict__ bih0, const float* __restrict__ bhh0,
    const float* __restrict__ Whr0,
    const float* __restrict__ Wihs, const float* __restrict__ Whhs,
    const float* __restrict__ bihs, const float* __restrict__ bhhs,
    const float* __restrict__ Whrs,
    float* __restrict__ out,
    unsigned* __restrict__ yR, unsigned* __restrict__ hR,
    unsigned* __restrict__ WP, unsigned* __restrict__ cnt)
{
  __shared__ float sG[64 * 128];    // 32 KB (full 64-batch x 128-gate tile)
  __shared__ float sBias[128];

  const int tid  = threadIdx.x;
  const int wg   = blockIdx.x;
  const int lane = tid & 63;
  const int wave = tid >> 6;
  const int lg   = wg >> 5;         // layer this WG serves (0..3)
  const int wgl  = wg & 31;         // index within layer group

  const int m1  = wave * 32 + (lane & 31);  // batch row
  const int n1  = lane & 31;                // local gate row (within tile)
  const int kh1 = (lane >> 5) * 8;

  // per-layer f32 weights/biases
  const float* Wih = (lg == 0) ? Wih0 : Wihs + (size_t)(lg - 1) * 4096 * 256;
  const float* Whh = (lg == 0) ? Whh0 : Whhs + (size_t)(lg - 1) * 4096 * 256;
  const float* bih = (lg == 0) ? bih0 : bihs + (size_t)(lg - 1) * 4096;
  const float* bhh = (lg == 0) ? bhh0 : bhhs + (size_t)(lg - 1) * 4096;
  const float* Whr = (lg == 0) ? Whr0 : Whrs + (size_t)(lg - 1) * 256 * 1024;
  // per-layer packed weights
  const unsigned* WPI = (lg == 0) ? WP + WP_W0I
                                  : WP + WP_WIS + (size_t)(lg - 1) * 1048576;
  const unsigned* WPH = (lg == 0) ? WP + WP_W0H
                                  : WP + WP_WHS + (size_t)(lg - 1) * 1048576;
  const unsigned* WPR = WP + WP_WR + (size_t)lg * 262144;
  const int KI = (lg == 0) ? D_ : P_;       // input-term K / Wih row stride

  unsigned* hP = hR + (size_t)lg * (B_ * H_);   // this layer's h (packed u32)

  // ---- prologue: pre-split all weights into WP (PK mode only) ----
  unsigned ep = 0;
  if (PK) {
    for (int c = wg * NTHR + tid; c < WP_CHUNKS; c += NWG * NTHR) {
      const float* src; unsigned* dst;
      int c0 = c;
      if (c0 < 262144) {
        src = Wih0 + (size_t)c0 * 8;  dst = WP + WP_W0I + (size_t)c0 * 8;
      } else if ((c0 -= 262144) < 131072) {
        src = Whh0 + (size_t)c0 * 8;  dst = WP + WP_W0H + (size_t)c0 * 8;
      } else if ((c0 -= 131072) < 393216) {
        src = Wihs + (size_t)c0 * 8;  dst = WP + WP_WIS + (size_t)c0 * 8;
      } else if ((c0 -= 393216) < 393216) {
        src = Whhs + (size_t)c0 * 8;  dst = WP + WP_WHS + (size_t)c0 * 8;
      } else {
        c0 -= 393216;
        src = (c0 < 32768) ? (Whr0 + (size_t)c0 * 8)
                           : (Whrs + (size_t)(c0 - 32768) * 8);
        dst = WP + WP_WR + (size_t)c0 * 8;
      }
      unsigned u[8];
#pragma unroll
      for (int i = 0; i < 8; ++i) u[i] = packf(src[i]);
#pragma unroll
      for (int i = 0; i < 4; ++i) {
        unsigned long long q = (unsigned long long)u[2 * i] |
                               ((unsigned long long)u[2 * i + 1] << 32);
        __hip_atomic_store((unsigned long long*)dst + i, q,
                           __ATOMIC_RELAXED, __HIP_MEMORY_SCOPE_AGENT);
      }
    }
  }
  ep++; gbar(cnt, ep);
  __threadfence();   // L1/L2 inv: cached reads of agent-written WP are fresh

  // bias staging: c -> unit (c>>2), gate (c&3)
  {
    int c = tid;
    int R = (c & 3) * H_ + wgl * 32 + (c >> 2);
    sBias[c] = bih[R] + bhh[R];
  }
  __syncthreads();

  float cs[16];   // cell state: batch b=tid>>1, units (tid&1)*16..+16
#pragma unroll
  for (int i = 0; i < 16; ++i) cs[i] = 0.f;

  const int R0 = (n1 & 3) * H_ + wgl * 32 + (n1 >> 2);  // tile T rows: R0+T*8

  for (int tick = 0; tick < T_ + 3; ++tick) {
    const int t = tick - lg;
    const bool act = (t >= 0) && (t < T_);

    // ========== phase 1: gates (4 n-tiles merged) + state update ==========
    if (act) {
      f32x16 aH[4] = {{}, {}, {}, {}};
      f32x16 aL[4] = {{}, {}, {}, {}};
      f32x16 aM[4] = {{}, {}, {}, {}};

      // ---- input term ----
      if (lg == 0) {
        const float* ax = x + ((size_t)m1 * T_ + t) * D_ + kh1;
#pragma unroll 2
        for (int k0 = 0; k0 < D_; k0 += 16) {
          short8 Ah, Al;
          split8(ax + k0, Ah, Al);
#pragma unroll
          for (int T = 0; T < 4; ++T) {
            short8 Bh, Bl;
            const size_t off = (size_t)(R0 + T * 8) * D_ + kh1 + k0;
            if (PK) unpack_c8(WPI + off, Bh, Bl);
            else    split8(Wih + off, Bh, Bl);
            aH[T] = __builtin_amdgcn_mfma_f32_32x32x16_bf16(Ah, Bh, aH[T], 0, 0, 0);
            aL[T] = __builtin_amdgcn_mfma_f32_32x32x16_bf16(Ah, Bl, aL[T], 0, 0, 0);
            aM[T] = __builtin_amdgcn_mfma_f32_32x32x16_bf16(Al, Bh, aM[T], 0, 0, 0);
          }
        }
      } else {
        const unsigned* ay = yR + (size_t)((lg - 1) * 2 + (t & 1)) * (B_ * P_)
                             + (size_t)m1 * P_ + kh1;
#pragma unroll 2
        for (int k0 = 0; k0 < P_; k0 += 16) {
          short8 Ah, Al;
          unpack_a8(ay + k0, Ah, Al);
#pragma unroll
          for (int T = 0; T < 4; ++T) {
            short8 Bh, Bl;
            const size_t off = (size_t)(R0 + T * 8) * P_ + kh1 + k0;
            if (PK) unpack_c8(WPI + off, Bh, Bl);
            else    split8(Wih + off, Bh, Bl);
            aH[T] = __builtin_amdgcn_mfma_f32_32x32x16_bf16(Ah, Bh, aH[T], 0, 0, 0);
            aL[T] = __builtin_amdgcn_mfma_f32_32x32x16_bf16(Ah, Bl, aL[T], 0, 0, 0);
            aM[T] = __builtin_amdgcn_mfma_f32_32x32x16_bf16(Al, Bh, aM[T], 0, 0, 0);
          }
        }
      }
      // ---- recurrent term y_l(t-1) ----
      if (t > 0) {
        const unsigned* ay = yR + (size_t)(lg * 2 + ((t - 1) & 1)) * (B_ * P_)
                             + (size_t)m1 * P_ + kh1;
#pragma unroll 2
        for (int k0 = 0; k0 < P_; k0 += 16) {
          short8 Ah, Al;
          unpack_a8(ay + k0, Ah, Al);
#pragma unroll
          for (int T = 0; T < 4; ++T) {
            short8 Bh, Bl;
            const size_t off = (size_t)(R0 + T * 8) * P_ + kh1 + k0;
            if (PK) unpack_c8(WPH + off, Bh, Bl);
            else    split8(Whh + off, Bh, Bl);
            aH[T] = __builtin_amdgcn_mfma_f32_32x32x16_bf16(Ah, Bh, aH[T], 0, 0, 0);
            aL[T] = __builtin_amdgcn_mfma_f32_32x32x16_bf16(Ah, Bl, aL[T], 0, 0, 0);
            aM[T] = __builtin_amdgcn_mfma_f32_32x32x16_bf16(Al, Bh, aM[T], 0, 0, 0);
          }
        }
      }
      // ---- writeback all 4 tiles: col = T*32 + n1 == unit*4 + gate ----
#pragma unroll
      for (int T = 0; T < 4; ++T) {
#pragma unroll
        for (int r = 0; r < 16; ++r) {
          int mrow = (r & 3) + 8 * (r >> 2) + 4 * (lane >> 5) + wave * 32;
          sG[mrow * 128 + T * 32 + n1] = aH[T][r] + aL[T][r] + aM[T][r];
        }
      }
      __syncthreads();
      // ---- elementwise: thread (b=tid>>1, q=tid&1) -> units q*16..+16 ----
      {
        const int b = tid >> 1, q = tid & 1;
        const float* gp = &sG[b * 128 + q * 64];
        const float* bp = &sBias[q * 64];
        unsigned pw[16];
#pragma unroll
        for (int j = 0; j < 16; ++j) {
          float ii = sigm(gp[j * 4 + 0] + bp[j * 4 + 0]);
          float ff = sigm(gp[j * 4 + 1] + bp[j * 4 + 1]);
          float gg = tanh_f(gp[j * 4 + 2] + bp[j * 4 + 2]);
          float oo = sigm(gp[j * 4 + 3] + bp[j * 4 + 3]);
          float cv = ff * cs[j] + ii * gg;
          cs[j] = cv;
          pw[j] = packf(oo * tanh_f(cv));
        }
        size_t ho = (size_t)b * H_ + wgl * 32 + q * 16;
#pragma unroll
        for (int j = 0; j < 8; ++j) {
          unsigned long long qq = (unsigned long long)pw[2 * j] |
                                  ((unsigned long long)pw[2 * j + 1] << 32);
          __hip_atomic_store((unsigned long long*)&hP[ho + 2 * j], qq,
                             __ATOMIC_RELAXED, __HIP_MEMORY_SCOPE_AGENT);
        }
      }
    }
    ep++; gbar(cnt, ep);

    // ========== phase 2: projection y_t = h @ Whr^T (2 K-halves) ==========
    if (act) {
      const int tile = wgl * 2 + wave;          // 0..63
      const int mt0  = (tile >> 4) * 16;        // batch block
      const int p0   = (tile & 15) * 16;        // proj-col block
      const int l16  = lane & 15;
      const int kh2  = (lane >> 4) * 8;
      const unsigned* ahp = hP + (size_t)(mt0 + l16) * H_ + kh2;
      f32x4 qA0 = {}, qA1 = {}, qA2 = {}, qB0 = {}, qB1 = {}, qB2 = {};
      if (PK) {
        const unsigned* wb = WPR + (size_t)(p0 + l16) * H_ + kh2;
#pragma unroll 2
        for (int k0 = 0; k0 < 512; k0 += 32) {
          short8 A1h, A1l, A2h, A2l, B1h, B1l, B2h, B2l;
          unpack_a8(ahp + k0, A1h, A1l);
          unpack_a8(ahp + 512 + k0, A2h, A2l);
          unpack_c8(wb + k0, B1h, B1l);
          unpack_c8(wb + 512 + k0, B2h, B2l);
          qA0 = __builtin_amdgcn_mfma_f32_16x16x32_bf16(A1h, B1h, qA0, 0, 0, 0);
          qA1 = __builtin_amdgcn_mfma_f32_16x16x32_bf16(A1h, B1l, qA1, 0, 0, 0);
          qA2 = __builtin_amdgcn_mfma_f32_16x16x32_bf16(A1l, B1h, qA2, 0, 0, 0);
          qB0 = __builtin_amdgcn_mfma_f32_16x16x32_bf16(A2h, B2h, qB0, 0, 0, 0);
          qB1 = __builtin_amdgcn_mfma_f32_16x16x32_bf16(A2h, B2l, qB1, 0, 0, 0);
          qB2 = __builtin_amdgcn_mfma_f32_16x16x32_bf16(A2l, B2h, qB2, 0, 0, 0);
        }
      } else {
        const float* wf = Whr + (size_t)(p0 + l16) * H_ + kh2;
#pragma unroll 2
        for (int k0 = 0; k0 < 512; k0 += 32) {
          short8 A1h, A1l, A2h, A2l, B1h, B1l, B2h, B2l;
          unpack_a8(ahp + k0, A1h, A1l);
          unpack_a8(ahp + 512 + k0, A2h, A2l);
          split8(wf + k0, B1h, B1l);
          split8(wf + 512 + k0, B2h, B2l);
          qA0 = __builtin_amdgcn_mfma_f32_16x16x32_bf16(A1h, B1h, qA0, 0, 0, 0);
          qA1 = __builtin_amdgcn_mfma_f32_16x16x32_bf16(A1h, B1l, qA1, 0, 0, 0);
          qA2 = __builtin_amdgcn_mfma_f32_16x16x32_bf16(A1l, B1h, qA2, 0, 0, 0);
          qB0 = __builtin_amdgcn_mfma_f32_16x16x32_bf16(A2h, B2h, qB0, 0, 0, 0);
          qB1 = __builtin_amdgcn_mfma_f32_16x16x32_bf16(A2h, B2l, qB1, 0, 0, 0);
          qB2 = __builtin_amdgcn_mfma_f32_16x16x32_bf16(A2l, B2h, qB2, 0, 0, 0);
        }
      }
      unsigned* yo = yR + (size_t)(lg * 2 + (t & 1)) * (B_ * P_);
#pragma unroll
      for (int r = 0; r < 4; ++r) {
        int mm = mt0 + (lane >> 4) * 4 + r;
        float v = (qA0[r] + qA1[r] + qA2[r]) + (qB0[r] + qB1[r] + qB2[r]);
        __hip_atomic_store(&yo[(size_t)mm * P_ + p0 + l16], packf(v),
                           __ATOMIC_RELAXED, __HIP_MEMORY_SCOPE_AGENT);
        if (lg == 3 && t == T_ - 1) out[mm * P_ + p0 + l16] = v;
      }
    }
    ep++; gbar(cnt, ep);
  }
}

extern "C" void kernel_launch(void* const* d_in, const int* in_sizes, int n_in,
                              void* d_out, int out_size, void* d_ws, size_t ws_size,
                              hipStream_t stream) {
  const float* x    = (const float*)d_in[0];
  const float* Wih0 = (const float*)d_in[1];
  const float* Whh0 = (const float*)d_in[2];
  const float* bih0 = (const float*)d_in[3];
  const float* bhh0 = (const float*)d_in[4];
  const float* Whr0 = (const float*)d_in[5];
  const float* Wihs = (const float*)d_in[6];
  const float* Whhs = (const float*)d_in[7];
  const float* bihs = (const float*)d_in[8];
  const float* bhhs = (const float*)d_in[9];
  const float* Whrs = (const float*)d_in[10];
  float* out = (float*)d_out;

  char* ws = (char*)d_ws;
  unsigned* cnt = (unsigned*)ws;                          // 4 KB
  unsigned* hR  = (unsigned*)(ws + 4096);                 // 4 x 256 KB
  unsigned* yR  = (unsigned*)(ws + 4096 + 1048576);       // 8 x 64 KB
  unsigned* WP  = (unsigned*)(ws + 1576960);              // 40 MB packed W
  const size_t need_pk = 1576960ull + 41943040ull;        // ~41.5 MB
  const bool pk = (ws_size >= need_pk);

  (void)hipMemsetAsync(d_ws, 0, 4096, stream);   // zero barrier counters

  void* args[] = {&x, &Wih0, &Whh0, &bih0, &bhh0, &Whr0,
                  &Wihs, &Whhs, &bihs, &bhhs, &Whrs,
                  &out, &yR, &hR, &WP, &cnt};
  hipError_t st;
  if (pk) {
    auto* kfn = lstm_kernel<true>;
    st = hipLaunchCooperativeKernel((void*)kfn, dim3(NWG), dim3(NTHR),
                                    args, 0, stream);
    if (st != hipSuccess)
      lstm_kernel<true><<<dim3(NWG), dim3(NTHR), 0, stream>>>(
          x, Wih0, Whh0, bih0, bhh0, Whr0, Wihs, Whhs, bihs, bhhs, Whrs,
          out, yR, hR, WP, cnt);
  } else {
    auto* kfn = lstm_kernel<false>;
    st = hipLaunchCooperativeKernel((void*)kfn, dim3(NWG), dim3(NTHR),
                                    args, 0, stream);
    if (st != hipSuccess)
      lstm_kernel<false><<<dim3(NWG), dim3(NTHR), 0, stream>>>(
          x, Wih0, Whh0, bih0, bhh0, Whr0, Wihs, Whhs, bihs, bhhs, Whrs,
          out, yR, hR, WP, cnt);
  }
}

// Round 9
// 12774.329 us; speedup vs baseline: 2.1731x; 1.6738x over previous
//
#include <hip/hip_runtime.h>
#include <cstdint>
#include <cstddef>

// 4-layer projected LSTM. B=64 T=256 D=512 H=1024 P=256. fp32 in/out.
// Split-bf16 (hi+lo) MFMA operands, 3 MFMAs per product (absmax ~6e-5).
//
// Round-15 (round-14 passed 21.4ms; counters: 26.5MB/tick weight streaming
// at 378 GB/s = outstanding-load-limited (1 wave/CU x ~16 lines ~= 400GB/s),
// NOT BW-bound (4.7% of peak)):
//   4x WAVES, CHAIN SPLIT ACROSS THEM. NTHR 128->512 (8 waves/WG, 4/CU):
//   wave = (batch-half, K-quarter).
//   - Phase-1: each wave does K/4 of the gate GEMM (chain 32 -> 8-12
//     stages) into private 12x f32x16 accs; 2 LDS gate copies, 2-step
//     (=, then +=) merge with intra-WG barriers; elementwise spread over
//     512 threads (4 units each).
//   - Phase-2: each 16x16 y-tile split over 4 K-quarter waves (chain
//     16 -> 8 stages), 4-partial LDS reduce.
//   Machine MLP x4 => weight streaming ~4x faster. Everything else
//   (wavefront skeleton, y rings, packed weights, gbar, launch fallback)
//   is the round-14 proven structure.
// Workspace: [cnt 4K][hR 1M][yR 512K][WP 40M] ~= 41.5 MB (fallback: f32 path).

#define B_ 64
#define T_ 256
#define D_ 512
#define H_ 1024
#define P_ 256
#define NWG 128
#define NTHR 512

using short8  = __attribute__((ext_vector_type(8))) short;
using f32x16  = __attribute__((ext_vector_type(16))) float;
using f32x4   = __attribute__((ext_vector_type(4))) float;

__device__ inline float bf2f(short s) {
  unsigned u = ((unsigned)(unsigned short)s) << 16;
  return __builtin_bit_cast(float, u);
}
__device__ inline unsigned short f2bf(float f) {
  unsigned u = __builtin_bit_cast(unsigned, f);
  u += 0x7fffu + ((u >> 16) & 1u);   // RTNE
  return (unsigned short)(u >> 16);
}
__device__ inline void split1(float v, short& hi, short& lo) {
  unsigned short h = f2bf(v);
  hi = (short)h;
  lo = (short)f2bf(v - bf2f((short)h));
}
__device__ inline unsigned packf(float v) {
  short h, l;
  split1(v, h, l);
  return (unsigned)(unsigned short)h | ((unsigned)(unsigned short)l << 16);
}
__device__ inline void split8(const float* p, short8& hi, short8& lo) {
  float4 a = *(const float4*)p;
  float4 b = *(const float4*)(p + 4);
  float v[8] = {a.x, a.y, a.z, a.w, b.x, b.y, b.z, b.w};
#pragma unroll
  for (int i = 0; i < 8; ++i) {
    short h, l;
    split1(v[i], h, l);
    hi[i] = h; lo[i] = l;
  }
}
// 8 packed elems via normal cached loads (pre-split weights)
__device__ inline void unpack_c8(const unsigned* p, short8& hi, short8& lo) {
  uint4 a = *(const uint4*)p;
  uint4 b = *(const uint4*)(p + 4);
  unsigned w[8] = {a.x, a.y, a.z, a.w, b.x, b.y, b.z, b.w};
#pragma unroll
  for (int i = 0; i < 8; ++i) {
    hi[i] = (short)(w[i] & 0xffff);
    lo[i] = (short)(w[i] >> 16);
  }
}
// 8 packed elems via agent-coherent loads (cross-WG h / y traffic)
__device__ inline void unpack_a8(const unsigned* p, short8& hi, short8& lo) {
#pragma unroll
  for (int i = 0; i < 4; ++i) {
    unsigned long long v = __hip_atomic_load((const unsigned long long*)p + i,
                                             __ATOMIC_RELAXED, __HIP_MEMORY_SCOPE_AGENT);
    unsigned w0 = (unsigned)v, w1 = (unsigned)(v >> 32);
    hi[2 * i]     = (short)(w0 & 0xffff);
    lo[2 * i]     = (short)(w0 >> 16);
    hi[2 * i + 1] = (short)(w1 & 0xffff);
    lo[2 * i + 1] = (short)(w1 >> 16);
  }
}
__device__ inline float sigm(float x)   { return 1.f / (1.f + __expf(-x)); }
__device__ inline float tanh_f(float x) { return 1.f - 2.f / (__expf(2.f * x) + 1.f); }

// Round-7 verified grid barrier. ep increases by exactly 1 per call.
#define NCNT 32
#define REL_IDX 768   // u32 index of release word (byte 3072, own line)
__device__ inline void gbar(unsigned* cnt, unsigned ep) {
  __syncthreads();   // compiler drains vmcnt before s_barrier: stores visible
  if (blockIdx.x == 0) {
    if (threadIdx.x < 64) {                // wave 0 scans in parallel
      if (threadIdx.x == 0)
        __hip_atomic_fetch_add(&cnt[0], 1u, __ATOMIC_RELAXED,
                               __HIP_MEMORY_SCOPE_AGENT);
      const unsigned tgt = ep * (NWG / NCNT);
      for (;;) {
        unsigned v = tgt;                  // lanes 32..63: trivially done
        if (threadIdx.x < NCNT)
          v = __hip_atomic_load(&cnt[threadIdx.x * 16], __ATOMIC_RELAXED,
                                __HIP_MEMORY_SCOPE_AGENT);
        if (__all(v >= tgt)) break;
        __builtin_amdgcn_s_sleep(2);
      }
      if (threadIdx.x == 0)
        __hip_atomic_store(&cnt[REL_IDX], ep, __ATOMIC_RELAXED,
                           __HIP_MEMORY_SCOPE_AGENT);
    }
  } else {
    if (threadIdx.x == 0) {
      __hip_atomic_fetch_add(&cnt[(blockIdx.x & (NCNT - 1)) * 16], 1u,
                             __ATOMIC_RELAXED, __HIP_MEMORY_SCOPE_AGENT);
      while (__hip_atomic_load(&cnt[REL_IDX], __ATOMIC_RELAXED,
                               __HIP_MEMORY_SCOPE_AGENT) < ep)
        __builtin_amdgcn_s_sleep(2);
    }
  }
  __syncthreads();
}

// packed-weight region offsets (u32 units): [W0I 2097152][W0H 1048576]
// [WIs 3x1048576][WHs 3x1048576][WR 4x262144] = 10485760 u32 = 40 MB.
#define WP_W0I 0
#define WP_W0H 2097152
#define WP_WIS 3145728
#define WP_WHS 6291456
#define WP_WR  9437184
#define WP_CHUNKS 1310720   // total 8-elem chunks

template <bool PK>
__global__ __launch_bounds__(NTHR) void lstm_kernel(
    const float* __restrict__ x,
    const float* __restrict__ Wih0, const float* __restrict__ Whh0,
    const float* __restrict__ bih0, const float* __restrict__ bhh0,
    const float* __restrict__ Whr0,
    const float* __restrict__ Wihs, const float* __restrict__ Whhs,
    const float* __restrict__ bihs, const float* __restrict__ bhhs,
    const float* __restrict__ Whrs,
    float* __restrict__ out,
    unsigned* __restrict__ yR, unsigned* __restrict__ hR,
    unsigned* __restrict__ WP, unsigned* __restrict__ cnt)
{
  __shared__ float sGA[64 * 128];   // 32 KB gate partial (k-quarters 0+1)
  __shared__ float sGB[64 * 128];   // 32 KB gate partial (k-quarters 2+3)
  __shared__ float sBias[128];
  __shared__ float sRed[8 * 64 * 4];  // 8 KB proj partials

  const int tid  = threadIdx.x;
  const int wg   = blockIdx.x;
  const int lane = tid & 63;
  const int wave = tid >> 6;        // 0..7
  const int bh   = wave & 1;        // batch half
  const int kq   = wave >> 1;       // K quarter (0..3)
  const int lg   = wg >> 5;         // layer this WG serves (0..3)
  const int wgl  = wg & 31;         // index within layer group

  const int m1  = bh * 32 + (lane & 31);    // batch row (phase 1)
  const int n1  = lane & 31;                // local gate row (within tile)
  const int kh1 = (lane >> 5) * 8;

  // per-layer f32 weights/biases
  const float* Wih = (lg == 0) ? Wih0 : Wihs + (size_t)(lg - 1) * 4096 * 256;
  const float* Whh = (lg == 0) ? Whh0 : Whhs + (size_t)(lg - 1) * 4096 * 256;
  const float* bih = (lg == 0) ? bih0 : bihs + (size_t)(lg - 1) * 4096;
  const float* bhh = (lg == 0) ? bhh0 : bhhs + (size_t)(lg - 1) * 4096;
  const float* Whr = (lg == 0) ? Whr0 : Whrs + (size_t)(lg - 1) * 256 * 1024;
  // per-layer packed weights
  const unsigned* WPI = (lg == 0) ? WP + WP_W0I
                                  : WP + WP_WIS + (size_t)(lg - 1) * 1048576;
  const unsigned* WPH = (lg == 0) ? WP + WP_W0H
                                  : WP + WP_WHS + (size_t)(lg - 1) * 1048576;
  const unsigned* WPR = WP + WP_WR + (size_t)lg * 262144;

  unsigned* hP = hR + (size_t)lg * (B_ * H_);   // this layer's h (packed u32)

  // ---- prologue: pre-split all weights into WP (PK mode only) ----
  unsigned ep = 0;
  if (PK) {
    for (int c = wg * NTHR + tid; c < WP_CHUNKS; c += NWG * NTHR) {
      const float* src; unsigned* dst;
      int c0 = c;
      if (c0 < 262144) {
        src = Wih0 + (size_t)c0 * 8;  dst = WP + WP_W0I + (size_t)c0 * 8;
      } else if ((c0 -= 262144) < 131072) {
        src = Whh0 + (size_t)c0 * 8;  dst = WP + WP_W0H + (size_t)c0 * 8;
      } else if ((c0 -= 131072) < 393216) {
        src = Wihs + (size_t)c0 * 8;  dst = WP + WP_WIS + (size_t)c0 * 8;
      } else if ((c0 -= 393216) < 393216) {
        src = Whhs + (size_t)c0 * 8;  dst = WP + WP_WHS + (size_t)c0 * 8;
      } else {
        c0 -= 393216;
        src = (c0 < 32768) ? (Whr0 + (size_t)c0 * 8)
                           : (Whrs + (size_t)(c0 - 32768) * 8);
        dst = WP + WP_WR + (size_t)c0 * 8;
      }
      unsigned u[8];
#pragma unroll
      for (int i = 0; i < 8; ++i) u[i] = packf(src[i]);
#pragma unroll
      for (int i = 0; i < 4; ++i) {
        unsigned long long q = (unsigned long long)u[2 * i] |
                               ((unsigned long long)u[2 * i + 1] << 32);
        __hip_atomic_store((unsigned long long*)dst + i, q,
                           __ATOMIC_RELAXED, __HIP_MEMORY_SCOPE_AGENT);
      }
    }
  }
  ep++; gbar(cnt, ep);
  __threadfence();   // L1/L2 inv: cached reads of agent-written WP are fresh

  // bias staging: c -> unit (c>>2), gate (c&3)
  if (tid < 128) {
    int c = tid;
    int R = (c & 3) * H_ + wgl * 32 + (c >> 2);
    sBias[c] = bih[R] + bhh[R];
  }
  __syncthreads();

  float cs[4];   // cell state: batch b=tid>>3, units (tid&7)*4 .. +4
#pragma unroll
  for (int i = 0; i < 4; ++i) cs[i] = 0.f;

  const int R0 = (n1 & 3) * H_ + wgl * 32 + (n1 >> 2);  // tile T rows: R0+T*8
  const int KQI = (lg == 0) ? 128 : 64;   // input-term K per quarter

  for (int tick = 0; tick < T_ + 3; ++tick) {
    const int t = tick - lg;
    const bool act = (t >= 0) && (t < T_);

    // ========== phase 1: gates (4 n-tiles, K split over 4 wave-pairs) ======
    if (act) {
      f32x16 aH[4] = {{}, {}, {}, {}};
      f32x16 aL[4] = {{}, {}, {}, {}};
      f32x16 aM[4] = {{}, {}, {}, {}};

      // ---- input term (this wave's K quarter) ----
      if (lg == 0) {
        const float* ax = x + ((size_t)m1 * T_ + t) * D_ + kh1;
#pragma unroll 2
        for (int k0 = kq * 128; k0 < kq * 128 + 128; k0 += 16) {
          short8 Ah, Al;
          split8(ax + k0, Ah, Al);
#pragma unroll
          for (int T = 0; T < 4; ++T) {
            short8 Bh, Bl;
            const size_t off = (size_t)(R0 + T * 8) * D_ + kh1 + k0;
            if (PK) unpack_c8(WPI + off, Bh, Bl);
            else    split8(Wih + off, Bh, Bl);
            aH[T] = __builtin_amdgcn_mfma_f32_32x32x16_bf16(Ah, Bh, aH[T], 0, 0, 0);
            aL[T] = __builtin_amdgcn_mfma_f32_32x32x16_bf16(Ah, Bl, aL[T], 0, 0, 0);
            aM[T] = __builtin_amdgcn_mfma_f32_32x32x16_bf16(Al, Bh, aM[T], 0, 0, 0);
          }
        }
      } else {
        const unsigned* ay = yR + (size_t)((lg - 1) * 2 + (t & 1)) * (B_ * P_)
                             + (size_t)m1 * P_ + kh1;
#pragma unroll 2
        for (int k0 = kq * 64; k0 < kq * 64 + 64; k0 += 16) {
          short8 Ah, Al;
          unpack_a8(ay + k0, Ah, Al);
#pragma unroll
          for (int T = 0; T < 4; ++T) {
            short8 Bh, Bl;
            const size_t off = (size_t)(R0 + T * 8) * P_ + kh1 + k0;
            if (PK) unpack_c8(WPI + off, Bh, Bl);
            else    split8(Wih + off, Bh, Bl);
            aH[T] = __builtin_amdgcn_mfma_f32_32x32x16_bf16(Ah, Bh, aH[T], 0, 0, 0);
            aL[T] = __builtin_amdgcn_mfma_f32_32x32x16_bf16(Ah, Bl, aL[T], 0, 0, 0);
            aM[T] = __builtin_amdgcn_mfma_f32_32x32x16_bf16(Al, Bh, aM[T], 0, 0, 0);
          }
        }
      }
      // ---- recurrent term y_l(t-1), this wave's K quarter ----
      if (t > 0) {
        const unsigned* ay = yR + (size_t)(lg * 2 + ((t - 1) & 1)) * (B_ * P_)
                             + (size_t)m1 * P_ + kh1;
#pragma unroll 2
        for (int k0 = kq * 64; k0 < kq * 64 + 64; k0 += 16) {
          short8 Ah, Al;
          unpack_a8(ay + k0, Ah, Al);
#pragma unroll
          for (int T = 0; T < 4; ++T) {
            short8 Bh, Bl;
            const size_t off = (size_t)(R0 + T * 8) * P_ + kh1 + k0;
            if (PK) unpack_c8(WPH + off, Bh, Bl);
            else    split8(Whh + off, Bh, Bl);
            aH[T] = __builtin_amdgcn_mfma_f32_32x32x16_bf16(Ah, Bh, aH[T], 0, 0, 0);
            aL[T] = __builtin_amdgcn_mfma_f32_32x32x16_bf16(Ah, Bl, aL[T], 0, 0, 0);
            aM[T] = __builtin_amdgcn_mfma_f32_32x32x16_bf16(Al, Bh, aM[T], 0, 0, 0);
          }
        }
      }
      // ---- merge k-quarters: {0,2} write =, barrier, {1,3} add += ----
      {
        float* sgc = (kq >= 2) ? sGB : sGA;
        if ((kq & 1) == 0) {
#pragma unroll
          for (int T = 0; T < 4; ++T)
#pragma unroll
            for (int r = 0; r < 16; ++r) {
              int mrow = (r & 3) + 8 * (r >> 2) + 4 * (lane >> 5) + bh * 32;
              sgc[mrow * 128 + T * 32 + n1] = aH[T][r] + aL[T][r] + aM[T][r];
            }
        }
        __syncthreads();
        if ((kq & 1) == 1) {
#pragma unroll
          for (int T = 0; T < 4; ++T)
#pragma unroll
            for (int r = 0; r < 16; ++r) {
              int mrow = (r & 3) + 8 * (r >> 2) + 4 * (lane >> 5) + bh * 32;
              sgc[mrow * 128 + T * 32 + n1] += aH[T][r] + aL[T][r] + aM[T][r];
            }
        }
        __syncthreads();
      }
      // ---- elementwise: thread -> batch b=tid>>3, 4 units (tid&7)*4.. ----
      {
        const int b  = tid >> 3;
        const int ub = (tid & 7) * 4;
        const float* gA = &sGA[b * 128];
        const float* gB = &sGB[b * 128];
        unsigned pw[4];
#pragma unroll
        for (int j = 0; j < 4; ++j) {
          int cb = (ub + j) * 4;
          float ii = sigm(gA[cb + 0] + gB[cb + 0] + sBias[cb + 0]);
          float ff = sigm(gA[cb + 1] + gB[cb + 1] + sBias[cb + 1]);
          float gg = tanh_f(gA[cb + 2] + gB[cb + 2] + sBias[cb + 2]);
          float oo = sigm(gA[cb + 3] + gB[cb + 3] + sBias[cb + 3]);
          float cv = ff * cs[j] + ii * gg;
          cs[j] = cv;
          pw[j] = packf(oo * tanh_f(cv));
        }
        size_t ho = (size_t)b * H_ + wgl * 32 + ub;
        unsigned long long q0 = (unsigned long long)pw[0] |
                                ((unsigned long long)pw[1] << 32);
        unsigned long long q1 = (unsigned long long)pw[2] |
                                ((unsigned long long)pw[3] << 32);
        __hip_atomic_store((unsigned long long*)&hP[ho], q0,
                           __ATOMIC_RELAXED, __HIP_MEMORY_SCOPE_AGENT);
        __hip_atomic_store((unsigned long long*)&hP[ho + 2], q1,
                           __ATOMIC_RELAXED, __HIP_MEMORY_SCOPE_AGENT);
      }
    }
    ep++; gbar(cnt, ep);

    // ========== phase 2: projection, 2 tiles x 4 K-quarter waves ==========
    if (act) {
      const int tile = wgl * 2 + (wave & 1);    // 0..63
      const int kq2  = wave >> 1;               // K quarter (0..3)
      const int mt0  = (tile >> 4) * 16;        // batch block
      const int p0   = (tile & 15) * 16;        // proj-col block
      const int l16  = lane & 15;
      const int kh2  = (lane >> 4) * 8 + kq2 * 256;
      const unsigned* ahp = hP + (size_t)(mt0 + l16) * H_ + kh2;
      f32x4 q0 = {}, q1 = {}, q2 = {};
      if (PK) {
        const unsigned* wb = WPR + (size_t)(p0 + l16) * H_ + kh2;
#pragma unroll 2
        for (int k0 = 0; k0 < 256; k0 += 32) {
          short8 Ah, Al, Bh, Bl;
          unpack_a8(ahp + k0, Ah, Al);
          unpack_c8(wb + k0, Bh, Bl);
          q0 = __builtin_amdgcn_mfma_f32_16x16x32_bf16(Ah, Bh, q0, 0, 0, 0);
          q1 = __builtin_amdgcn_mfma_f32_16x16x32_bf16(Ah, Bl, q1, 0, 0, 0);
          q2 = __builtin_amdgcn_mfma_f32_16x16x32_bf16(Al, Bh, q2, 0, 0, 0);
        }
      } else {
        const float* wf = Whr + (size_t)(p0 + l16) * H_ + kh2;
#pragma unroll 2
        for (int k0 = 0; k0 < 256; k0 += 32) {
          short8 Ah, Al, Bh, Bl;
          unpack_a8(ahp + k0, Ah, Al);
          split8(wf + k0, Bh, Bl);
          q0 = __builtin_amdgcn_mfma_f32_16x16x32_bf16(Ah, Bh, q0, 0, 0, 0);
          q1 = __builtin_amdgcn_mfma_f32_16x16x32_bf16(Ah, Bl, q1, 0, 0, 0);
          q2 = __builtin_amdgcn_mfma_f32_16x16x32_bf16(Al, Bh, q2, 0, 0, 0);
        }
      }
      f32x4 a4;
#pragma unroll
      for (int r = 0; r < 4; ++r) a4[r] = q0[r] + q1[r] + q2[r];
      *(f32x4*)&sRed[(wave * 64 + lane) * 4] = a4;
      __syncthreads();
      if (kq2 == 0) {   // waves 0,1 reduce their tile's 4 partials
        f32x4 p1 = *(const f32x4*)&sRed[((wave + 2) * 64 + lane) * 4];
        f32x4 p2 = *(const f32x4*)&sRed[((wave + 4) * 64 + lane) * 4];
        f32x4 p3 = *(const f32x4*)&sRed[((wave + 6) * 64 + lane) * 4];
        unsigned* yo = yR + (size_t)(lg * 2 + (t & 1)) * (B_ * P_);
#pragma unroll
        for (int r = 0; r < 4; ++r) {
          int mm = mt0 + (lane >> 4) * 4 + r;
          float v = a4[r] + p1[r] + p2[r] + p3[r];
          __hip_atomic_store(&yo[(size_t)mm * P_ + p0 + l16], packf(v),
                             __ATOMIC_RELAXED, __HIP_MEMORY_SCOPE_AGENT);
          if (lg == 3 && t == T_ - 1) out[mm * P_ + p0 + l16] = v;
        }
      }
    }
    ep++; gbar(cnt, ep);
  }
}

extern "C" void kernel_launch(void* const* d_in, const int* in_sizes, int n_in,
                              void* d_out, int out_size, void* d_ws, size_t ws_size,
                              hipStream_t stream) {
  const float* x    = (const float*)d_in[0];
  const float* Wih0 = (const float*)d_in[1];
  const float* Whh0 = (const float*)d_in[2];
  const float* bih0 = (const float*)d_in[3];
  const float* bhh0 = (const float*)d_in[4];
  const float* Whr0 = (const float*)d_in[5];
  const float* Wihs = (const float*)d_in[6];
  const float* Whhs = (const float*)d_in[7];
  const float* bihs = (const float*)d_in[8];
  const float* bhhs = (const float*)d_in[9];
  const float* Whrs = (const float*)d_in[10];
  float* out = (float*)d_out;

  char* ws = (char*)d_ws;
  unsigned* cnt = (unsigned*)ws;                          // 4 KB
  unsigned* hR  = (unsigned*)(ws + 4096);                 // 4 x 256 KB
  unsigned* yR  = (unsigned*)(ws + 4096 + 1048576);       // 8 x 64 KB
  unsigned* WP  = (unsigned*)(ws + 1576960);              // 40 MB packed W
  const size_t need_pk = 1576960ull + 41943040ull;        // ~41.5 MB
  const bool pk = (ws_size >= need_pk);

  (void)hipMemsetAsync(d_ws, 0, 4096, stream);   // zero barrier counters

  void* args[] = {&x, &Wih0, &Whh0, &bih0, &bhh0, &Whr0,
                  &Wihs, &Whhs, &bihs, &bhhs, &Whrs,
                  &out, &yR, &hR, &WP, &cnt};
  hipError_t st;
  if (pk) {
    auto* kfn = lstm_kernel<true>;
    st = hipLaunchCooperativeKernel((void*)kfn, dim3(NWG), dim3(NTHR),
                                    args, 0, stream);
    if (st != hipSuccess)
      lstm_kernel<true><<<dim3(NWG), dim3(NTHR), 0, stream>>>(
          x, Wih0, Whh0, bih0, bhh0, Whr0, Wihs, Whhs, bihs, bhhs, Whrs,
          out, yR, hR, WP, cnt);
  } else {
    auto* kfn = lstm_kernel<false>;
    st = hipLaunchCooperativeKernel((void*)kfn, dim3(NWG), dim3(NTHR),
                                    args, 0, stream);
    if (st != hipSuccess)
      lstm_kernel<false><<<dim3(NWG), dim3(NTHR), 0, stream>>>(
          x, Wih0, Whh0, bih0, bhh0, Whr0, Wihs, Whhs, bihs, bhhs, Whrs,
          out, yR, hR, WP, cnt);
  }
}

// Round 10
// 8119.419 us; speedup vs baseline: 3.4190x; 1.5733x over previous
//
#include <hip/hip_runtime.h>
#include <cstdint>
#include <cstddef>

// 4-layer projected LSTM. B=64 T=256 D=512 H=1024 P=256. fp32 in/out.
// Split-bf16 (hi+lo) MFMA operands, 3 MFMAs per product (absmax ~6e-5).
//
// Round-16 (round-15 passed 12.77ms; MLP model CONFIRMED: hbm 378->670GB/s
// scaled with wave count; ~42us of 49us/tick = weight streaming at 670GB/s,
// 10x below BW ceiling; NWG=128 leaves HALF the CUs idle):
//   DOUBLE THE GRID: NWG 128->256 (64 WGs/layer, 16 H-units each), NTHR
//   stays 512. Machine waves 1024->2048 => aggregate MLP x2 => streaming
//   rate ~x2.
//   - Phase-1: 2 n-tiles/WG (6 MFMA chains/wave), wave=(batch-half,
//     K-quarter), 2-copy LDS merge as before.
//   - Phase-2: 1 16x16 y-tile/WG split over 8 K-eighth waves (chain 4
//     stages), 8-partial LDS reduce by wave 0.
//   Everything else (wavefront skeleton, y rings, packed weights, gbar,
//   launch fallback) is the round-15 proven structure; gbar target
//   (ep*NWG/NCNT) adapts via the NWG define.
// Workspace: [cnt 4K][hR 1M][yR 512K][WP 40M] ~= 41.5 MB (fallback: f32 path).

#define B_ 64
#define T_ 256
#define D_ 512
#define H_ 1024
#define P_ 256
#define NWG 256
#define NTHR 512

using short8  = __attribute__((ext_vector_type(8))) short;
using f32x16  = __attribute__((ext_vector_type(16))) float;
using f32x4   = __attribute__((ext_vector_type(4))) float;

__device__ inline float bf2f(short s) {
  unsigned u = ((unsigned)(unsigned short)s) << 16;
  return __builtin_bit_cast(float, u);
}
__device__ inline unsigned short f2bf(float f) {
  unsigned u = __builtin_bit_cast(unsigned, f);
  u += 0x7fffu + ((u >> 16) & 1u);   // RTNE
  return (unsigned short)(u >> 16);
}
__device__ inline void split1(float v, short& hi, short& lo) {
  unsigned short h = f2bf(v);
  hi = (short)h;
  lo = (short)f2bf(v - bf2f((short)h));
}
__device__ inline unsigned packf(float v) {
  short h, l;
  split1(v, h, l);
  return (unsigned)(unsigned short)h | ((unsigned)(unsigned short)l << 16);
}
__device__ inline void split8(const float* p, short8& hi, short8& lo) {
  float4 a = *(const float4*)p;
  float4 b = *(const float4*)(p + 4);
  float v[8] = {a.x, a.y, a.z, a.w, b.x, b.y, b.z, b.w};
#pragma unroll
  for (int i = 0; i < 8; ++i) {
    short h, l;
    split1(v[i], h, l);
    hi[i] = h; lo[i] = l;
  }
}
// 8 packed elems via normal cached loads (pre-split weights)
__device__ inline void unpack_c8(const unsigned* p, short8& hi, short8& lo) {
  uint4 a = *(const uint4*)p;
  uint4 b = *(const uint4*)(p + 4);
  unsigned w[8] = {a.x, a.y, a.z, a.w, b.x, b.y, b.z, b.w};
#pragma unroll
  for (int i = 0; i < 8; ++i) {
    hi[i] = (short)(w[i] & 0xffff);
    lo[i] = (short)(w[i] >> 16);
  }
}
// 8 packed elems via agent-coherent loads (cross-WG h / y traffic)
__device__ inline void unpack_a8(const unsigned* p, short8& hi, short8& lo) {
#pragma unroll
  for (int i = 0; i < 4; ++i) {
    unsigned long long v = __hip_atomic_load((const unsigned long long*)p + i,
                                             __ATOMIC_RELAXED, __HIP_MEMORY_SCOPE_AGENT);
    unsigned w0 = (unsigned)v, w1 = (unsigned)(v >> 32);
    hi[2 * i]     = (short)(w0 & 0xffff);
    lo[2 * i]     = (short)(w0 >> 16);
    hi[2 * i + 1] = (short)(w1 & 0xffff);
    lo[2 * i + 1] = (short)(w1 >> 16);
  }
}
__device__ inline float sigm(float x)   { return 1.f / (1.f + __expf(-x)); }
__device__ inline float tanh_f(float x) { return 1.f - 2.f / (__expf(2.f * x) + 1.f); }

// Round-7 verified grid barrier. ep increases by exactly 1 per call.
#define NCNT 32
#define REL_IDX 768   // u32 index of release word (byte 3072, own line)
__device__ inline void gbar(unsigned* cnt, unsigned ep) {
  __syncthreads();   // compiler drains vmcnt before s_barrier: stores visible
  if (blockIdx.x == 0) {
    if (threadIdx.x < 64) {                // wave 0 scans in parallel
      if (threadIdx.x == 0)
        __hip_atomic_fetch_add(&cnt[0], 1u, __ATOMIC_RELAXED,
                               __HIP_MEMORY_SCOPE_AGENT);
      const unsigned tgt = ep * (NWG / NCNT);
      for (;;) {
        unsigned v = tgt;                  // lanes 32..63: trivially done
        if (threadIdx.x < NCNT)
          v = __hip_atomic_load(&cnt[threadIdx.x * 16], __ATOMIC_RELAXED,
                                __HIP_MEMORY_SCOPE_AGENT);
        if (__all(v >= tgt)) break;
        __builtin_amdgcn_s_sleep(2);
      }
      if (threadIdx.x == 0)
        __hip_atomic_store(&cnt[REL_IDX], ep, __ATOMIC_RELAXED,
                           __HIP_MEMORY_SCOPE_AGENT);
    }
  } else {
    if (threadIdx.x == 0) {
      __hip_atomic_fetch_add(&cnt[(blockIdx.x & (NCNT - 1)) * 16], 1u,
                             __ATOMIC_RELAXED, __HIP_MEMORY_SCOPE_AGENT);
      while (__hip_atomic_load(&cnt[REL_IDX], __ATOMIC_RELAXED,
                               __HIP_MEMORY_SCOPE_AGENT) < ep)
        __builtin_amdgcn_s_sleep(2);
    }
  }
  __syncthreads();
}

// packed-weight region offsets (u32 units): [W0I 2097152][W0H 1048576]
// [WIs 3x1048576][WHs 3x1048576][WR 4x262144] = 10485760 u32 = 40 MB.
#define WP_W0I 0
#define WP_W0H 2097152
#define WP_WIS 3145728
#define WP_WHS 6291456
#define WP_WR  9437184
#define WP_CHUNKS 1310720   // total 8-elem chunks

template <bool PK>
__global__ __launch_bounds__(NTHR) void lstm_kernel(
    const float* __restrict__ x,
    const float* __restrict__ Wih0, const float* __restrict__ Whh0,
    const float* __restrict__ bih0, const float* __restrict__ bhh0,
    const float* __restrict__ Whr0,
    const float* __restrict__ Wihs, const float* __restrict__ Whhs,
    const float* __restrict__ bihs, const float* __restrict__ bhhs,
    const float* __restrict__ Whrs,
    float* __restrict__ out,
    unsigned* __restrict__ yR, unsigned* __restrict__ hR,
    unsigned* __restrict__ WP, unsigned* __restrict__ cnt)
{
  __shared__ float sGA[64 * 64];    // 16 KB gate partial (k-quarters 0+1)
  __shared__ float sGB[64 * 64];    // 16 KB gate partial (k-quarters 2+3)
  __shared__ float sBias[64];
  __shared__ float sRed[8 * 64 * 4];  // 8 KB proj partials

  const int tid  = threadIdx.x;
  const int wg   = blockIdx.x;
  const int lane = tid & 63;
  const int wave = tid >> 6;        // 0..7
  const int bh   = wave & 1;        // batch half (phase 1)
  const int kq   = wave >> 1;       // K quarter (phase 1, 0..3)
  const int lg   = wg >> 6;         // layer this WG serves (0..3)
  const int wgl  = wg & 63;         // index within layer group (0..63)

  const int m1  = bh * 32 + (lane & 31);    // batch row (phase 1)
  const int n1  = lane & 31;                // local gate row (within tile)
  const int kh1 = (lane >> 5) * 8;

  // per-layer f32 weights/biases
  const float* Wih = (lg == 0) ? Wih0 : Wihs + (size_t)(lg - 1) * 4096 * 256;
  const float* Whh = (lg == 0) ? Whh0 : Whhs + (size_t)(lg - 1) * 4096 * 256;
  const float* bih = (lg == 0) ? bih0 : bihs + (size_t)(lg - 1) * 4096;
  const float* bhh = (lg == 0) ? bhh0 : bhhs + (size_t)(lg - 1) * 4096;
  const float* Whr = (lg == 0) ? Whr0 : Whrs + (size_t)(lg - 1) * 256 * 1024;
  // per-layer packed weights
  const unsigned* WPI = (lg == 0) ? WP + WP_W0I
                                  : WP + WP_WIS + (size_t)(lg - 1) * 1048576;
  const unsigned* WPH = (lg == 0) ? WP + WP_W0H
                                  : WP + WP_WHS + (size_t)(lg - 1) * 1048576;
  const unsigned* WPR = WP + WP_WR + (size_t)lg * 262144;

  unsigned* hP = hR + (size_t)lg * (B_ * H_);   // this layer's h (packed u32)

  // ---- prologue: pre-split all weights into WP (PK mode only) ----
  unsigned ep = 0;
  if (PK) {
    for (int c = wg * NTHR + tid; c < WP_CHUNKS; c += NWG * NTHR) {
      const float* src; unsigned* dst;
      int c0 = c;
      if (c0 < 262144) {
        src = Wih0 + (size_t)c0 * 8;  dst = WP + WP_W0I + (size_t)c0 * 8;
      } else if ((c0 -= 262144) < 131072) {
        src = Whh0 + (size_t)c0 * 8;  dst = WP + WP_W0H + (size_t)c0 * 8;
      } else if ((c0 -= 131072) < 393216) {
        src = Wihs + (size_t)c0 * 8;  dst = WP + WP_WIS + (size_t)c0 * 8;
      } else if ((c0 -= 393216) < 393216) {
        src = Whhs + (size_t)c0 * 8;  dst = WP + WP_WHS + (size_t)c0 * 8;
      } else {
        c0 -= 393216;
        src = (c0 < 32768) ? (Whr0 + (size_t)c0 * 8)
                           : (Whrs + (size_t)(c0 - 32768) * 8);
        dst = WP + WP_WR + (size_t)c0 * 8;
      }
      unsigned u[8];
#pragma unroll
      for (int i = 0; i < 8; ++i) u[i] = packf(src[i]);
#pragma unroll
      for (int i = 0; i < 4; ++i) {
        unsigned long long q = (unsigned long long)u[2 * i] |
                               ((unsigned long long)u[2 * i + 1] << 32);
        __hip_atomic_store((unsigned long long*)dst + i, q,
                           __ATOMIC_RELAXED, __HIP_MEMORY_SCOPE_AGENT);
      }
    }
  }
  ep++; gbar(cnt, ep);
  __threadfence();   // L1/L2 inv: cached reads of agent-written WP are fresh

  // bias staging: c in 0..63 -> unit (c>>2), gate (c&3)
  if (tid < 64) {
    int c = tid;
    int R = (c & 3) * H_ + wgl * 16 + (c >> 2);
    sBias[c] = bih[R] + bhh[R];
  }
  __syncthreads();

  float cs[2];   // cell state: batch b=tid>>3, units (tid&7)*2 .. +2
  cs[0] = 0.f; cs[1] = 0.f;

  const int R0 = (n1 & 3) * H_ + wgl * 16 + (n1 >> 2);  // tile T rows: R0+T*8

  for (int tick = 0; tick < T_ + 3; ++tick) {
    const int t = tick - lg;
    const bool act = (t >= 0) && (t < T_);

    // ========== phase 1: gates (2 n-tiles, K split over 4 wave-pairs) ======
    if (act) {
      f32x16 aH[2] = {{}, {}};
      f32x16 aL[2] = {{}, {}};
      f32x16 aM[2] = {{}, {}};

      // ---- input term (this wave's K quarter) ----
      if (lg == 0) {
        const float* ax = x + ((size_t)m1 * T_ + t) * D_ + kh1;
#pragma unroll 2
        for (int k0 = kq * 128; k0 < kq * 128 + 128; k0 += 16) {
          short8 Ah, Al;
          split8(ax + k0, Ah, Al);
#pragma unroll
          for (int T = 0; T < 2; ++T) {
            short8 Bh, Bl;
            const size_t off = (size_t)(R0 + T * 8) * D_ + kh1 + k0;
            if (PK) unpack_c8(WPI + off, Bh, Bl);
            else    split8(Wih + off, Bh, Bl);
            aH[T] = __builtin_amdgcn_mfma_f32_32x32x16_bf16(Ah, Bh, aH[T], 0, 0, 0);
            aL[T] = __builtin_amdgcn_mfma_f32_32x32x16_bf16(Ah, Bl, aL[T], 0, 0, 0);
            aM[T] = __builtin_amdgcn_mfma_f32_32x32x16_bf16(Al, Bh, aM[T], 0, 0, 0);
          }
        }
      } else {
        const unsigned* ay = yR + (size_t)((lg - 1) * 2 + (t & 1)) * (B_ * P_)
                             + (size_t)m1 * P_ + kh1;
#pragma unroll 2
        for (int k0 = kq * 64; k0 < kq * 64 + 64; k0 += 16) {
          short8 Ah, Al;
          unpack_a8(ay + k0, Ah, Al);
#pragma unroll
          for (int T = 0; T < 2; ++T) {
            short8 Bh, Bl;
            const size_t off = (size_t)(R0 + T * 8) * P_ + kh1 + k0;
            if (PK) unpack_c8(WPI + off, Bh, Bl);
            else    split8(Wih + off, Bh, Bl);
            aH[T] = __builtin_amdgcn_mfma_f32_32x32x16_bf16(Ah, Bh, aH[T], 0, 0, 0);
            aL[T] = __builtin_amdgcn_mfma_f32_32x32x16_bf16(Ah, Bl, aL[T], 0, 0, 0);
            aM[T] = __builtin_amdgcn_mfma_f32_32x32x16_bf16(Al, Bh, aM[T], 0, 0, 0);
          }
        }
      }
      // ---- recurrent term y_l(t-1), this wave's K quarter ----
      if (t > 0) {
        const unsigned* ay = yR + (size_t)(lg * 2 + ((t - 1) & 1)) * (B_ * P_)
                             + (size_t)m1 * P_ + kh1;
#pragma unroll 2
        for (int k0 = kq * 64; k0 < kq * 64 + 64; k0 += 16) {
          short8 Ah, Al;
          unpack_a8(ay + k0, Ah, Al);
#pragma unroll
          for (int T = 0; T < 2; ++T) {
            short8 Bh, Bl;
            const size_t off = (size_t)(R0 + T * 8) * P_ + kh1 + k0;
            if (PK) unpack_c8(WPH + off, Bh, Bl);
            else    split8(Whh + off, Bh, Bl);
            aH[T] = __builtin_amdgcn_mfma_f32_32x32x16_bf16(Ah, Bh, aH[T], 0, 0, 0);
            aL[T] = __builtin_amdgcn_mfma_f32_32x32x16_bf16(Ah, Bl, aL[T], 0, 0, 0);
            aM[T] = __builtin_amdgcn_mfma_f32_32x32x16_bf16(Al, Bh, aM[T], 0, 0, 0);
          }
        }
      }
      // ---- merge k-quarters: {0,2} write =, barrier, {1,3} add += ----
      {
        float* sgc = (kq >= 2) ? sGB : sGA;
        if ((kq & 1) == 0) {
#pragma unroll
          for (int T = 0; T < 2; ++T)
#pragma unroll
            for (int r = 0; r < 16; ++r) {
              int mrow = (r & 3) + 8 * (r >> 2) + 4 * (lane >> 5) + bh * 32;
              sgc[mrow * 64 + T * 32 + n1] = aH[T][r] + aL[T][r] + aM[T][r];
            }
        }
        __syncthreads();
        if ((kq & 1) == 1) {
#pragma unroll
          for (int T = 0; T < 2; ++T)
#pragma unroll
            for (int r = 0; r < 16; ++r) {
              int mrow = (r & 3) + 8 * (r >> 2) + 4 * (lane >> 5) + bh * 32;
              sgc[mrow * 64 + T * 32 + n1] += aH[T][r] + aL[T][r] + aM[T][r];
            }
        }
        __syncthreads();
      }
      // ---- elementwise: thread -> batch b=tid>>3, 2 units (tid&7)*2.. ----
      {
        const int b  = tid >> 3;
        const int ub = (tid & 7) * 2;
        const float* gA = &sGA[b * 64];
        const float* gB = &sGB[b * 64];
        unsigned pw[2];
#pragma unroll
        for (int j = 0; j < 2; ++j) {
          int cb = (ub + j) * 4;
          float ii = sigm(gA[cb + 0] + gB[cb + 0] + sBias[cb + 0]);
          float ff = sigm(gA[cb + 1] + gB[cb + 1] + sBias[cb + 1]);
          float gg = tanh_f(gA[cb + 2] + gB[cb + 2] + sBias[cb + 2]);
          float oo = sigm(gA[cb + 3] + gB[cb + 3] + sBias[cb + 3]);
          float cv = ff * cs[j] + ii * gg;
          cs[j] = cv;
          pw[j] = packf(oo * tanh_f(cv));
        }
        size_t ho = (size_t)b * H_ + wgl * 16 + ub;
        unsigned long long q0 = (unsigned long long)pw[0] |
                                ((unsigned long long)pw[1] << 32);
        __hip_atomic_store((unsigned long long*)&hP[ho], q0,
                           __ATOMIC_RELAXED, __HIP_MEMORY_SCOPE_AGENT);
      }
    }
    ep++; gbar(cnt, ep);

    // ========== phase 2: projection, 1 tile x 8 K-eighth waves ==========
    if (act) {
      const int mt0  = (wgl >> 4) * 16;         // batch block
      const int p0   = (wgl & 15) * 16;         // proj-col block
      const int l16  = lane & 15;
      const int kh2  = (lane >> 4) * 8 + wave * 128;
      const unsigned* ahp = hP + (size_t)(mt0 + l16) * H_ + kh2;
      f32x4 q0 = {}, q1 = {}, q2 = {};
      if (PK) {
        const unsigned* wb = WPR + (size_t)(p0 + l16) * H_ + kh2;
#pragma unroll 2
        for (int k0 = 0; k0 < 128; k0 += 32) {
          short8 Ah, Al, Bh, Bl;
          unpack_a8(ahp + k0, Ah, Al);
          unpack_c8(wb + k0, Bh, Bl);
          q0 = __builtin_amdgcn_mfma_f32_16x16x32_bf16(Ah, Bh, q0, 0, 0, 0);
          q1 = __builtin_amdgcn_mfma_f32_16x16x32_bf16(Ah, Bl, q1, 0, 0, 0);
          q2 = __builtin_amdgcn_mfma_f32_16x16x32_bf16(Al, Bh, q2, 0, 0, 0);
        }
      } else {
        const float* wf = Whr + (size_t)(p0 + l16) * H_ + kh2;
#pragma unroll 2
        for (int k0 = 0; k0 < 128; k0 += 32) {
          short8 Ah, Al, Bh, Bl;
          unpack_a8(ahp + k0, Ah, Al);
          split8(wf + k0, Bh, Bl);
          q0 = __builtin_amdgcn_mfma_f32_16x16x32_bf16(Ah, Bh, q0, 0, 0, 0);
          q1 = __builtin_amdgcn_mfma_f32_16x16x32_bf16(Ah, Bl, q1, 0, 0, 0);
          q2 = __builtin_amdgcn_mfma_f32_16x16x32_bf16(Al, Bh, q2, 0, 0, 0);
        }
      }
      f32x4 a4;
#pragma unroll
      for (int r = 0; r < 4; ++r) a4[r] = q0[r] + q1[r] + q2[r];
      *(f32x4*)&sRed[(wave * 64 + lane) * 4] = a4;
      __syncthreads();
      if (wave == 0) {   // reduce 8 partials for this tile
        float v4[4];
#pragma unroll
        for (int r = 0; r < 4; ++r) v4[r] = a4[r];
#pragma unroll
        for (int w = 1; w < 8; ++w) {
          f32x4 pw = *(const f32x4*)&sRed[(w * 64 + lane) * 4];
#pragma unroll
          for (int r = 0; r < 4; ++r) v4[r] += pw[r];
        }
        unsigned* yo = yR + (size_t)(lg * 2 + (t & 1)) * (B_ * P_);
#pragma unroll
        for (int r = 0; r < 4; ++r) {
          int mm = mt0 + (lane >> 4) * 4 + r;
          __hip_atomic_store(&yo[(size_t)mm * P_ + p0 + l16], packf(v4[r]),
                             __ATOMIC_RELAXED, __HIP_MEMORY_SCOPE_AGENT);
          if (lg == 3 && t == T_ - 1) out[mm * P_ + p0 + l16] = v4[r];
        }
      }
    }
    ep++; gbar(cnt, ep);
  }
}

extern "C" void kernel_launch(void* const* d_in, const int* in_sizes, int n_in,
                              void* d_out, int out_size, void* d_ws, size_t ws_size,
                              hipStream_t stream) {
  const float* x    = (const float*)d_in[0];
  const float* Wih0 = (const float*)d_in[1];
  const float* Whh0 = (const float*)d_in[2];
  const float* bih0 = (const float*)d_in[3];
  const float* bhh0 = (const float*)d_in[4];
  const float* Whr0 = (const float*)d_in[5];
  const float* Wihs = (const float*)d_in[6];
  const float* Whhs = (const float*)d_in[7];
  const float* bihs = (const float*)d_in[8];
  const float* bhhs = (const float*)d_in[9];
  const float* Whrs = (const float*)d_in[10];
  float* out = (float*)d_out;

  char* ws = (char*)d_ws;
  unsigned* cnt = (unsigned*)ws;                          // 4 KB
  unsigned* hR  = (unsigned*)(ws + 4096);                 // 4 x 256 KB
  unsigned* yR  = (unsigned*)(ws + 4096 + 1048576);       // 8 x 64 KB
  unsigned* WP  = (unsigned*)(ws + 1576960);              // 40 MB packed W
  const size_t need_pk = 1576960ull + 41943040ull;        // ~41.5 MB
  const bool pk = (ws_size >= need_pk);

  (void)hipMemsetAsync(d_ws, 0, 4096, stream);   // zero barrier counters

  void* args[] = {&x, &Wih0, &Whh0, &bih0, &bhh0, &Whr0,
                  &Wihs, &Whhs, &bihs, &bhhs, &Whrs,
                  &out, &yR, &hR, &WP, &cnt};
  hipError_t st;
  if (pk) {
    auto* kfn = lstm_kernel<true>;
    st = hipLaunchCooperativeKernel((void*)kfn, dim3(NWG), dim3(NTHR),
                                    args, 0, stream);
    if (st != hipSuccess)
      lstm_kernel<true><<<dim3(NWG), dim3(NTHR), 0, stream>>>(
          x, Wih0, Whh0, bih0, bhh0, Whr0, Wihs, Whhs, bihs, bhhs, Whrs,
          out, yR, hR, WP, cnt);
  } else {
    auto* kfn = lstm_kernel<false>;
    st = hipLaunchCooperativeKernel((void*)kfn, dim3(NWG), dim3(NTHR),
                                    args, 0, stream);
    if (st != hipSuccess)
      lstm_kernel<false><<<dim3(NWG), dim3(NTHR), 0, stream>>>(
          x, Wih0, Whh0, bih0, bhh0, Whr0, Wihs, Whhs, bihs, bhhs, Whrs,
          out, yR, hR, WP, cnt);
  }
}

// Round 11
// 7251.501 us; speedup vs baseline: 3.8282x; 1.1197x over previous
//
#include <hip/hip_runtime.h>
#include <cstdint>
#include <cstddef>

// 4-layer projected LSTM. B=64 T=256 D=512 H=1024 P=256. fp32 in/out.
// Split-bf16 (hi+lo) MFMA operands, 3 MFMAs per product (absmax ~6e-5).
//
// Round-17 (round-16 passed 8.12ms; 25.8MB/tick weight re-streaming at
// 920GB/s = 28us of the 31us tick; per-XCD L2 (4MB) thrashes vs 6.4MB
// working set => weights re-fetched from HBM all 259 ticks):
//   PIN THE WEIGHTS ON-CHIP (PIN template, ws>=52MB):
//   - W_ih (l>0) + W_hh: LDS-resident per WG (64KB+64KB packed u32,
//     stride 260 to spread banks; staged once -- layer is WG-permanent).
//   - W_hr slice: register-resident (32 u32/lane).
//   - Layer-0 W_ih0 (K=512, no recurrence dep): input-gates computed 4
//     ticks per group in the phase-2 slot (weights read once/4 ticks ->
//     2MB/tick amortized), merged into an 8MB f32 ring, added in the
//     elementwise step.
//   - Phase-1 K-quarter merge: single sG, 4-step (=,+=,+=,+=) intra-WG.
//   Per-tick HBM traffic 25.8MB -> ~3MB. Fallback<false> (small ws) =
//   round-16 streaming path verbatim. LDS 158KB (PIN) / 41KB (fallback).
// Workspace: [cnt 4K][hR 1M][yR 512K][gI 8M][WP 40M] ~= 49.5 MB.

#define B_ 64
#define T_ 256
#define D_ 512
#define H_ 1024
#define P_ 256
#define NWG 256
#define NTHR 512
#define WST 260    // pinned-weight LDS row stride (u32): 16B-aligned, 4-way banks

using short8  = __attribute__((ext_vector_type(8))) short;
using f32x16  = __attribute__((ext_vector_type(16))) float;
using f32x4   = __attribute__((ext_vector_type(4))) float;

__device__ inline float bf2f(short s) {
  unsigned u = ((unsigned)(unsigned short)s) << 16;
  return __builtin_bit_cast(float, u);
}
__device__ inline unsigned short f2bf(float f) {
  unsigned u = __builtin_bit_cast(unsigned, f);
  u += 0x7fffu + ((u >> 16) & 1u);   // RTNE
  return (unsigned short)(u >> 16);
}
__device__ inline void split1(float v, short& hi, short& lo) {
  unsigned short h = f2bf(v);
  hi = (short)h;
  lo = (short)f2bf(v - bf2f((short)h));
}
__device__ inline unsigned packf(float v) {
  short h, l;
  split1(v, h, l);
  return (unsigned)(unsigned short)h | ((unsigned)(unsigned short)l << 16);
}
__device__ inline void split8(const float* p, short8& hi, short8& lo) {
  float4 a = *(const float4*)p;
  float4 b = *(const float4*)(p + 4);
  float v[8] = {a.x, a.y, a.z, a.w, b.x, b.y, b.z, b.w};
#pragma unroll
  for (int i = 0; i < 8; ++i) {
    short h, l;
    split1(v[i], h, l);
    hi[i] = h; lo[i] = l;
  }
}
// 8 packed elems via normal loads (global cached OR LDS via generic ptr)
__device__ inline void unpack_c8(const unsigned* p, short8& hi, short8& lo) {
  uint4 a = *(const uint4*)p;
  uint4 b = *(const uint4*)(p + 4);
  unsigned w[8] = {a.x, a.y, a.z, a.w, b.x, b.y, b.z, b.w};
#pragma unroll
  for (int i = 0; i < 8; ++i) {
    hi[i] = (short)(w[i] & 0xffff);
    lo[i] = (short)(w[i] >> 16);
  }
}
// 8 packed elems via agent-coherent loads (cross-WG h / y traffic)
__device__ inline void unpack_a8(const unsigned* p, short8& hi, short8& lo) {
#pragma unroll
  for (int i = 0; i < 4; ++i) {
    unsigned long long v = __hip_atomic_load((const unsigned long long*)p + i,
                                             __ATOMIC_RELAXED, __HIP_MEMORY_SCOPE_AGENT);
    unsigned w0 = (unsigned)v, w1 = (unsigned)(v >> 32);
    hi[2 * i]     = (short)(w0 & 0xffff);
    lo[2 * i]     = (short)(w0 >> 16);
    hi[2 * i + 1] = (short)(w1 & 0xffff);
    lo[2 * i + 1] = (short)(w1 >> 16);
  }
}
__device__ inline float sigm(float x)   { return 1.f / (1.f + __expf(-x)); }
__device__ inline float tanh_f(float x) { return 1.f - 2.f / (__expf(2.f * x) + 1.f); }

// Round-7 verified grid barrier. ep increases by exactly 1 per call.
#define NCNT 32
#define REL_IDX 768   // u32 index of release word (byte 3072, own line)
__device__ inline void gbar(unsigned* cnt, unsigned ep) {
  __syncthreads();   // compiler drains vmcnt before s_barrier: stores visible
  if (blockIdx.x == 0) {
    if (threadIdx.x < 64) {                // wave 0 scans in parallel
      if (threadIdx.x == 0)
        __hip_atomic_fetch_add(&cnt[0], 1u, __ATOMIC_RELAXED,
                               __HIP_MEMORY_SCOPE_AGENT);
      const unsigned tgt = ep * (NWG / NCNT);
      for (;;) {
        unsigned v = tgt;                  // lanes 32..63: trivially done
        if (threadIdx.x < NCNT)
          v = __hip_atomic_load(&cnt[threadIdx.x * 16], __ATOMIC_RELAXED,
                                __HIP_MEMORY_SCOPE_AGENT);
        if (__all(v >= tgt)) break;
        __builtin_amdgcn_s_sleep(2);
      }
      if (threadIdx.x == 0)
        __hip_atomic_store(&cnt[REL_IDX], ep, __ATOMIC_RELAXED,
                           __HIP_MEMORY_SCOPE_AGENT);
    }
  } else {
    if (threadIdx.x == 0) {
      __hip_atomic_fetch_add(&cnt[(blockIdx.x & (NCNT - 1)) * 16], 1u,
                             __ATOMIC_RELAXED, __HIP_MEMORY_SCOPE_AGENT);
      while (__hip_atomic_load(&cnt[REL_IDX], __ATOMIC_RELAXED,
                               __HIP_MEMORY_SCOPE_AGENT) < ep)
        __builtin_amdgcn_s_sleep(2);
    }
  }
  __syncthreads();
}

// packed-weight region offsets (u32 units): [W0I 2097152][W0H 1048576]
// [WIs 3x1048576][WHs 3x1048576][WR 4x262144] = 10485760 u32 = 40 MB.
#define WP_W0I 0
#define WP_W0H 2097152
#define WP_WIS 3145728
#define WP_WHS 6291456
#define WP_WR  9437184
#define WP_CHUNKS 1310720   // total 8-elem chunks

template <bool PIN>
__global__ __launch_bounds__(NTHR) void lstm_kernel(
    const float* __restrict__ x,
    const float* __restrict__ Wih0, const float* __restrict__ Whh0,
    const float* __restrict__ bih0, const float* __restrict__ bhh0,
    const float* __restrict__ Whr0,
    const float* __restrict__ Wihs, const float* __restrict__ Whhs,
    const float* __restrict__ bihs, const float* __restrict__ bhhs,
    const float* __restrict__ Whrs,
    float* __restrict__ out,
    unsigned* __restrict__ yR, unsigned* __restrict__ hR,
    unsigned* __restrict__ WP, float* __restrict__ gI,
    unsigned* __restrict__ cnt)
{
  __shared__ unsigned sWI[PIN ? 64 * WST : 1];   // pinned W_ih (l>0)
  __shared__ unsigned sWH[PIN ? 64 * WST : 1];   // pinned W_hh
  __shared__ float sG [PIN ? 64 * 64 : 1];       // PIN: single gate buffer
  __shared__ float sGA[PIN ? 1 : 64 * 64];       // fallback: partial A
  __shared__ float sGB[PIN ? 1 : 64 * 64];       // fallback: partial B
  __shared__ float sRed[8 * 64 * 4];             // 8 KB proj partials
  __shared__ float sBias[64];

  const int tid  = threadIdx.x;
  const int wg   = blockIdx.x;
  const int lane = tid & 63;
  const int wave = tid >> 6;        // 0..7
  const int bh   = wave & 1;        // batch half (phase 1)
  const int kq   = wave >> 1;       // K quarter (phase 1, 0..3)
  const int lg   = wg >> 6;         // layer this WG serves (0..3)
  const int wgl  = wg & 63;         // index within layer group (0..63)

  const int m1  = bh * 32 + (lane & 31);    // batch row (phase 1)
  const int n1  = lane & 31;                // local gate row (within tile)
  const int kh1 = (lane >> 5) * 8;

  // per-layer f32 weights/biases
  const float* Wih = (lg == 0) ? Wih0 : Wihs + (size_t)(lg - 1) * 4096 * 256;
  const float* Whh = (lg == 0) ? Whh0 : Whhs + (size_t)(lg - 1) * 4096 * 256;
  const float* bih = (lg == 0) ? bih0 : bihs + (size_t)(lg - 1) * 4096;
  const float* bhh = (lg == 0) ? bhh0 : bhhs + (size_t)(lg - 1) * 4096;
  const float* Whr = (lg == 0) ? Whr0 : Whrs + (size_t)(lg - 1) * 256 * 1024;
  // per-layer packed weights
  const unsigned* WPI = (lg == 0) ? WP + WP_W0I
                                  : WP + WP_WIS + (size_t)(lg - 1) * 1048576;
  const unsigned* WPH = (lg == 0) ? WP + WP_W0H
                                  : WP + WP_WHS + (size_t)(lg - 1) * 1048576;
  const unsigned* WPR = WP + WP_WR + (size_t)lg * 262144;

  unsigned* hP = hR + (size_t)lg * (B_ * H_);   // this layer's h (packed u32)
  float*    myRing = gI + (size_t)wgl * 32768;  // l0 only: 8 slots x 4096 f32

  // ---- prologue: pre-split all weights into WP (PIN mode only) ----
  unsigned ep = 0;
  if (PIN) {
    for (int c = wg * NTHR + tid; c < WP_CHUNKS; c += NWG * NTHR) {
      const float* src; unsigned* dst;
      int c0 = c;
      if (c0 < 262144) {
        src = Wih0 + (size_t)c0 * 8;  dst = WP + WP_W0I + (size_t)c0 * 8;
      } else if ((c0 -= 262144) < 131072) {
        src = Whh0 + (size_t)c0 * 8;  dst = WP + WP_W0H + (size_t)c0 * 8;
      } else if ((c0 -= 131072) < 393216) {
        src = Wihs + (size_t)c0 * 8;  dst = WP + WP_WIS + (size_t)c0 * 8;
      } else if ((c0 -= 393216) < 393216) {
        src = Whhs + (size_t)c0 * 8;  dst = WP + WP_WHS + (size_t)c0 * 8;
      } else {
        c0 -= 393216;
        src = (c0 < 32768) ? (Whr0 + (size_t)c0 * 8)
                           : (Whrs + (size_t)(c0 - 32768) * 8);
        dst = WP + WP_WR + (size_t)c0 * 8;
      }
      unsigned u[8];
#pragma unroll
      for (int i = 0; i < 8; ++i) u[i] = packf(src[i]);
#pragma unroll
      for (int i = 0; i < 4; ++i) {
        unsigned long long q = (unsigned long long)u[2 * i] |
                               ((unsigned long long)u[2 * i + 1] << 32);
        __hip_atomic_store((unsigned long long*)dst + i, q,
                           __ATOMIC_RELAXED, __HIP_MEMORY_SCOPE_AGENT);
      }
    }
  }
  ep++; gbar(cnt, ep);
  __threadfence();   // L1/L2 inv: cached reads of agent-written WP are fresh

  // bias staging: c in 0..63 -> unit (c>>2), gate (c&3)
  if (tid < 64) {
    int c = tid;
    int R = (c & 3) * H_ + wgl * 16 + (c >> 2);
    sBias[c] = bih[R] + bhh[R];
  }

  // ---- PIN: stage pinned weights (LDS slice row s=T*32+n1 -> W row R(s)) ----
  if (PIN) {
    if (lg > 0) {
      for (int idx = tid; idx < 64 * 32; idx += NTHR) {
        int s = idx >> 5, c = (idx & 31) * 8;
        int R = ((s & 31) & 3) * H_ + wgl * 16 + ((s & 31) >> 2) + (s >> 5) * 8;
        const unsigned* src = WPI + (size_t)R * 256 + c;
        uint4 a = *(const uint4*)src, b = *(const uint4*)(src + 4);
        *(uint4*)&sWI[s * WST + c] = a;
        *(uint4*)&sWI[s * WST + c + 4] = b;
      }
    }
    for (int idx = tid; idx < 64 * 32; idx += NTHR) {
      int s = idx >> 5, c = (idx & 31) * 8;
      int R = ((s & 31) & 3) * H_ + wgl * 16 + ((s & 31) >> 2) + (s >> 5) * 8;
      const unsigned* src = WPH + (size_t)R * 256 + c;
      uint4 a = *(const uint4*)src, b = *(const uint4*)(src + 4);
      *(uint4*)&sWH[s * WST + c] = a;
      *(uint4*)&sWH[s * WST + c + 4] = b;
    }
  }
  __syncthreads();

  // ---- PIN: W_hr slice into registers (32 u32/lane) ----
  unsigned wr[32];
  const int l16p = lane & 15;
  const int kh2p = (lane >> 4) * 8 + wave * 128;
  if (PIN) {
    const unsigned* wb = WPR + (size_t)((wgl & 15) * 16 + l16p) * 1024 + kh2p;
#pragma unroll
    for (int k = 0; k < 4; ++k)
#pragma unroll
      for (int j = 0; j < 8; ++j) wr[k * 8 + j] = wb[k * 32 + j];
  }

  const int R0 = (n1 & 3) * H_ + wgl * 16 + (n1 >> 2);  // tile T rows: R0+T*8

  // ---- l0 4-tick input-gate group GEMM (PIN): x@Wih0 for ticks tg..tg+3 ----
  auto group_in = [&](int tg) {
    f32x16 ac[2][4] = {{{}, {}, {}, {}}, {{}, {}, {}, {}}};
    for (int k0 = kq * 128; k0 < kq * 128 + 128; k0 += 16) {
      short8 B0h, B0l, B1h, B1l;
      unpack_c8(WPI + (size_t)R0 * 512 + kh1 + k0, B0h, B0l);
      unpack_c8(WPI + (size_t)(R0 + 8) * 512 + kh1 + k0, B1h, B1l);
#pragma unroll
      for (int st = 0; st < 4; ++st) {
        short8 Ah, Al;
        split8(x + ((size_t)m1 * T_ + tg + st) * D_ + kh1 + k0, Ah, Al);
        ac[0][st] = __builtin_amdgcn_mfma_f32_32x32x16_bf16(Ah, B0h, ac[0][st], 0, 0, 0);
        ac[0][st] = __builtin_amdgcn_mfma_f32_32x32x16_bf16(Ah, B0l, ac[0][st], 0, 0, 0);
        ac[0][st] = __builtin_amdgcn_mfma_f32_32x32x16_bf16(Al, B0h, ac[0][st], 0, 0, 0);
        ac[1][st] = __builtin_amdgcn_mfma_f32_32x32x16_bf16(Ah, B1h, ac[1][st], 0, 0, 0);
        ac[1][st] = __builtin_amdgcn_mfma_f32_32x32x16_bf16(Ah, B1l, ac[1][st], 0, 0, 0);
        ac[1][st] = __builtin_amdgcn_mfma_f32_32x32x16_bf16(Al, B1h, ac[1][st], 0, 0, 0);
      }
    }
#pragma unroll
    for (int st = 0; st < 4; ++st) {
#pragma unroll
      for (int step = 0; step < 4; ++step) {
        if (kq == step) {
#pragma unroll
          for (int T = 0; T < 2; ++T)
#pragma unroll
            for (int r = 0; r < 16; ++r) {
              int mrow = (r & 3) + 8 * (r >> 2) + 4 * (lane >> 5) + bh * 32;
              if (step == 0) sG[mrow * 64 + T * 32 + n1]  = ac[T][st][r];
              else           sG[mrow * 64 + T * 32 + n1] += ac[T][st][r];
            }
        }
        __syncthreads();
      }
      float* ring = myRing + ((tg + st) & 7) * 4096;
      for (int i = tid; i < 1024; i += NTHR)
        ((float4*)ring)[i] = ((const float4*)sG)[i];
      __syncthreads();
    }
  };
  if (PIN && lg == 0) group_in(0);

  float cs[2];   // cell state: batch b=tid>>3, units (tid&7)*2 .. +2
  cs[0] = 0.f; cs[1] = 0.f;

  for (int tick = 0; tick < T_ + 3; ++tick) {
    const int t = tick - lg;
    const bool act = (t >= 0) && (t < T_);

    // ================= phase 1: gates + state update =================
    if (act) {
      f32x16 aH[2] = {{}, {}};
      f32x16 aL[2] = {{}, {}};
      f32x16 aM[2] = {{}, {}};

      if (PIN) {
        // ---- input term from pinned sWI (l>0; l0 uses the ring) ----
        if (lg > 0) {
          const unsigned* ay = yR + (size_t)((lg - 1) * 2 + (t & 1)) * (B_ * P_)
                               + (size_t)m1 * P_ + kh1;
#pragma unroll 2
          for (int k0 = kq * 64; k0 < kq * 64 + 64; k0 += 16) {
            short8 Ah, Al;
            unpack_a8(ay + k0, Ah, Al);
#pragma unroll
            for (int T = 0; T < 2; ++T) {
              short8 Bh, Bl;
              unpack_c8(&sWI[(T * 32 + n1) * WST + kh1 + k0], Bh, Bl);
              aH[T] = __builtin_amdgcn_mfma_f32_32x32x16_bf16(Ah, Bh, aH[T], 0, 0, 0);
              aL[T] = __builtin_amdgcn_mfma_f32_32x32x16_bf16(Ah, Bl, aL[T], 0, 0, 0);
              aM[T] = __builtin_amdgcn_mfma_f32_32x32x16_bf16(Al, Bh, aM[T], 0, 0, 0);
            }
          }
        }
        // ---- recurrent term from pinned sWH ----
        if (t > 0) {
          const unsigned* ay = yR + (size_t)(lg * 2 + ((t - 1) & 1)) * (B_ * P_)
                               + (size_t)m1 * P_ + kh1;
#pragma unroll 2
          for (int k0 = kq * 64; k0 < kq * 64 + 64; k0 += 16) {
            short8 Ah, Al;
            unpack_a8(ay + k0, Ah, Al);
#pragma unroll
            for (int T = 0; T < 2; ++T) {
              short8 Bh, Bl;
              unpack_c8(&sWH[(T * 32 + n1) * WST + kh1 + k0], Bh, Bl);
              aH[T] = __builtin_amdgcn_mfma_f32_32x32x16_bf16(Ah, Bh, aH[T], 0, 0, 0);
              aL[T] = __builtin_amdgcn_mfma_f32_32x32x16_bf16(Ah, Bl, aL[T], 0, 0, 0);
              aM[T] = __builtin_amdgcn_mfma_f32_32x32x16_bf16(Al, Bh, aM[T], 0, 0, 0);
            }
          }
        }
        // ---- 4-step merge into single sG ----
#pragma unroll
        for (int step = 0; step < 4; ++step) {
          if (kq == step) {
#pragma unroll
            for (int T = 0; T < 2; ++T)
#pragma unroll
              for (int r = 0; r < 16; ++r) {
                int mrow = (r & 3) + 8 * (r >> 2) + 4 * (lane >> 5) + bh * 32;
                float v = aH[T][r] + aL[T][r] + aM[T][r];
                if (step == 0) sG[mrow * 64 + T * 32 + n1]  = v;
                else           sG[mrow * 64 + T * 32 + n1] += v;
              }
          }
          __syncthreads();
        }
        // ---- elementwise (+ l0 ring input) ----
        {
          const int b  = tid >> 3;
          const int ub = (tid & 7) * 2;
          const float* gp = &sG[b * 64];
          const float* rp = myRing + (t & 7) * 4096 + b * 64;
          unsigned pw[2];
#pragma unroll
          for (int j = 0; j < 2; ++j) {
            int cb = (ub + j) * 4;
            float g0 = gp[cb + 0], g1 = gp[cb + 1], g2 = gp[cb + 2], g3 = gp[cb + 3];
            if (lg == 0) { g0 += rp[cb + 0]; g1 += rp[cb + 1];
                           g2 += rp[cb + 2]; g3 += rp[cb + 3]; }
            float ii = sigm(g0 + sBias[cb + 0]);
            float ff = sigm(g1 + sBias[cb + 1]);
            float gg = tanh_f(g2 + sBias[cb + 2]);
            float oo = sigm(g3 + sBias[cb + 3]);
            float cv = ff * cs[j] + ii * gg;
            cs[j] = cv;
            pw[j] = packf(oo * tanh_f(cv));
          }
          size_t ho = (size_t)(tid >> 3) * H_ + wgl * 16 + ub;
          unsigned long long q0 = (unsigned long long)pw[0] |
                                  ((unsigned long long)pw[1] << 32);
          __hip_atomic_store((unsigned long long*)&hP[ho], q0,
                             __ATOMIC_RELAXED, __HIP_MEMORY_SCOPE_AGENT);
        }
      } else {
        // ================= fallback: round-16 streaming path =============
        if (lg == 0) {
          const float* ax = x + ((size_t)m1 * T_ + t) * D_ + kh1;
#pragma unroll 2
          for (int k0 = kq * 128; k0 < kq * 128 + 128; k0 += 16) {
            short8 Ah, Al;
            split8(ax + k0, Ah, Al);
#pragma unroll
            for (int T = 0; T < 2; ++T) {
              short8 Bh, Bl;
              split8(Wih + (size_t)(R0 + T * 8) * D_ + kh1 + k0, Bh, Bl);
              aH[T] = __builtin_amdgcn_mfma_f32_32x32x16_bf16(Ah, Bh, aH[T], 0, 0, 0);
              aL[T] = __builtin_amdgcn_mfma_f32_32x32x16_bf16(Ah, Bl, aL[T], 0, 0, 0);
              aM[T] = __builtin_amdgcn_mfma_f32_32x32x16_bf16(Al, Bh, aM[T], 0, 0, 0);
            }
          }
        } else {
          const unsigned* ay = yR + (size_t)((lg - 1) * 2 + (t & 1)) * (B_ * P_)
                               + (size_t)m1 * P_ + kh1;
#pragma unroll 2
          for (int k0 = kq * 64; k0 < kq * 64 + 64; k0 += 16) {
            short8 Ah, Al;
            unpack_a8(ay + k0, Ah, Al);
#pragma unroll
            for (int T = 0; T < 2; ++T) {
              short8 Bh, Bl;
              split8(Wih + (size_t)(R0 + T * 8) * P_ + kh1 + k0, Bh, Bl);
              aH[T] = __builtin_amdgcn_mfma_f32_32x32x16_bf16(Ah, Bh, aH[T], 0, 0, 0);
              aL[T] = __builtin_amdgcn_mfma_f32_32x32x16_bf16(Ah, Bl, aL[T], 0, 0, 0);
              aM[T] = __builtin_amdgcn_mfma_f32_32x32x16_bf16(Al, Bh, aM[T], 0, 0, 0);
            }
          }
        }
        if (t > 0) {
          const unsigned* ay = yR + (size_t)(lg * 2 + ((t - 1) & 1)) * (B_ * P_)
                               + (size_t)m1 * P_ + kh1;
#pragma unroll 2
          for (int k0 = kq * 64; k0 < kq * 64 + 64; k0 += 16) {
            short8 Ah, Al;
            unpack_a8(ay + k0, Ah, Al);
#pragma unroll
            for (int T = 0; T < 2; ++T) {
              short8 Bh, Bl;
              split8(Whh + (size_t)(R0 + T * 8) * P_ + kh1 + k0, Bh, Bl);
              aH[T] = __builtin_amdgcn_mfma_f32_32x32x16_bf16(Ah, Bh, aH[T], 0, 0, 0);
              aL[T] = __builtin_amdgcn_mfma_f32_32x32x16_bf16(Ah, Bl, aL[T], 0, 0, 0);
              aM[T] = __builtin_amdgcn_mfma_f32_32x32x16_bf16(Al, Bh, aM[T], 0, 0, 0);
            }
          }
        }
        {
          float* sgc = (kq >= 2) ? sGB : sGA;
          if ((kq & 1) == 0) {
#pragma unroll
            for (int T = 0; T < 2; ++T)
#pragma unroll
              for (int r = 0; r < 16; ++r) {
                int mrow = (r & 3) + 8 * (r >> 2) + 4 * (lane >> 5) + bh * 32;
                sgc[mrow * 64 + T * 32 + n1] = aH[T][r] + aL[T][r] + aM[T][r];
              }
          }
          __syncthreads();
          if ((kq & 1) == 1) {
#pragma unroll
            for (int T = 0; T < 2; ++T)
#pragma unroll
              for (int r = 0; r < 16; ++r) {
                int mrow = (r & 3) + 8 * (r >> 2) + 4 * (lane >> 5) + bh * 32;
                sgc[mrow * 64 + T * 32 + n1] += aH[T][r] + aL[T][r] + aM[T][r];
              }
          }
          __syncthreads();
        }
        {
          const int b  = tid >> 3;
          const int ub = (tid & 7) * 2;
          const float* gA = &sGA[b * 64];
          const float* gB = &sGB[b * 64];
          unsigned pw[2];
#pragma unroll
          for (int j = 0; j < 2; ++j) {
            int cb = (ub + j) * 4;
            float ii = sigm(gA[cb + 0] + gB[cb + 0] + sBias[cb + 0]);
            float ff = sigm(gA[cb + 1] + gB[cb + 1] + sBias[cb + 1]);
            float gg = tanh_f(gA[cb + 2] + gB[cb + 2] + sBias[cb + 2]);
            float oo = sigm(gA[cb + 3] + gB[cb + 3] + sBias[cb + 3]);
            float cv = ff * cs[j] + ii * gg;
            cs[j] = cv;
            pw[j] = packf(oo * tanh_f(cv));
          }
          size_t ho = (size_t)b * H_ + wgl * 16 + ub;
          unsigned long long q0 = (unsigned long long)pw[0] |
                                  ((unsigned long long)pw[1] << 32);
          __hip_atomic_store((unsigned long long*)&hP[ho], q0,
                             __ATOMIC_RELAXED, __HIP_MEMORY_SCOPE_AGENT);
        }
      }
    }
    ep++; gbar(cnt, ep);

    // ========== phase 2: projection, 1 tile x 8 K-eighth waves ==========
    if (act) {
      const int mt0  = (wgl >> 4) * 16;         // batch block
      const int p0   = (wgl & 15) * 16;         // proj-col block
      const unsigned* ahp = hP + (size_t)(mt0 + l16p) * H_ + kh2p;
      f32x4 q0 = {}, q1 = {}, q2 = {};
      if (PIN) {
#pragma unroll
        for (int k = 0; k < 4; ++k) {
          short8 Ah, Al, Bh, Bl;
          unpack_a8(ahp + k * 32, Ah, Al);
#pragma unroll
          for (int j = 0; j < 8; ++j) {
            Bh[j] = (short)(wr[k * 8 + j] & 0xffff);
            Bl[j] = (short)(wr[k * 8 + j] >> 16);
          }
          q0 = __builtin_amdgcn_mfma_f32_16x16x32_bf16(Ah, Bh, q0, 0, 0, 0);
          q1 = __builtin_amdgcn_mfma_f32_16x16x32_bf16(Ah, Bl, q1, 0, 0, 0);
          q2 = __builtin_amdgcn_mfma_f32_16x16x32_bf16(Al, Bh, q2, 0, 0, 0);
        }
      } else {
        const float* wf = Whr + (size_t)(p0 + l16p) * H_ + kh2p;
#pragma unroll 2
        for (int k0 = 0; k0 < 128; k0 += 32) {
          short8 Ah, Al, Bh, Bl;
          unpack_a8(ahp + k0, Ah, Al);
          split8(wf + k0, Bh, Bl);
          q0 = __builtin_amdgcn_mfma_f32_16x16x32_bf16(Ah, Bh, q0, 0, 0, 0);
          q1 = __builtin_amdgcn_mfma_f32_16x16x32_bf16(Ah, Bl, q1, 0, 0, 0);
          q2 = __builtin_amdgcn_mfma_f32_16x16x32_bf16(Al, Bh, q2, 0, 0, 0);
        }
      }
      f32x4 a4;
#pragma unroll
      for (int r = 0; r < 4; ++r) a4[r] = q0[r] + q1[r] + q2[r];
      *(f32x4*)&sRed[(wave * 64 + lane) * 4] = a4;
      __syncthreads();
      if (wave == 0) {   // reduce 8 partials for this tile
        float v4[4];
#pragma unroll
        for (int r = 0; r < 4; ++r) v4[r] = a4[r];
#pragma unroll
        for (int w = 1; w < 8; ++w) {
          f32x4 pw = *(const f32x4*)&sRed[(w * 64 + lane) * 4];
#pragma unroll
          for (int r = 0; r < 4; ++r) v4[r] += pw[r];
        }
        unsigned* yo = yR + (size_t)(lg * 2 + (t & 1)) * (B_ * P_);
#pragma unroll
        for (int r = 0; r < 4; ++r) {
          int mm = mt0 + (lane >> 4) * 4 + r;
          __hip_atomic_store(&yo[(size_t)mm * P_ + p0 + l16p], packf(v4[r]),
                             __ATOMIC_RELAXED, __HIP_MEMORY_SCOPE_AGENT);
          if (lg == 3 && t == T_ - 1) out[mm * P_ + p0 + l16p] = v4[r];
        }
      }
      // ---- l0: next 4-tick input-gate group (weights read once / 4 ticks) --
      if (PIN && lg == 0 && (t & 3) == 3 && t + 1 < T_) group_in(t + 1);
    }
    ep++; gbar(cnt, ep);
  }
}

extern "C" void kernel_launch(void* const* d_in, const int* in_sizes, int n_in,
                              void* d_out, int out_size, void* d_ws, size_t ws_size,
                              hipStream_t stream) {
  const float* x    = (const float*)d_in[0];
  const float* Wih0 = (const float*)d_in[1];
  const float* Whh0 = (const float*)d_in[2];
  const float* bih0 = (const float*)d_in[3];
  const float* bhh0 = (const float*)d_in[4];
  const float* Whr0 = (const float*)d_in[5];
  const float* Wihs = (const float*)d_in[6];
  const float* Whhs = (const float*)d_in[7];
  const float* bihs = (const float*)d_in[8];
  const float* bhhs = (const float*)d_in[9];
  const float* Whrs = (const float*)d_in[10];
  float* out = (float*)d_out;

  char* ws = (char*)d_ws;
  unsigned* cnt = (unsigned*)ws;                          // 4 KB
  unsigned* hR  = (unsigned*)(ws + 4096);                 // 4 x 256 KB
  unsigned* yR  = (unsigned*)(ws + 1052672);              // 8 x 64 KB
  float*    gI  = (float*)(ws + 1576960);                 // 8 MB l0 gate ring
  unsigned* WP  = (unsigned*)(ws + 9965568);              // 40 MB packed W
  const size_t need_pin = 9965568ull + 41943040ull;       // ~49.5 MB
  const bool pin = (ws_size >= need_pin);

  (void)hipMemsetAsync(d_ws, 0, 4096, stream);   // zero barrier counters

  void* args[] = {&x, &Wih0, &Whh0, &bih0, &bhh0, &Whr0,
                  &Wihs, &Whhs, &bihs, &bhhs, &Whrs,
                  &out, &yR, &hR, &WP, &gI, &cnt};
  hipError_t st;
  if (pin) {
    auto* kfn = lstm_kernel<true>;
    st = hipLaunchCooperativeKernel((void*)kfn, dim3(NWG), dim3(NTHR),
                                    args, 0, stream);
    if (st != hipSuccess)
      lstm_kernel<true><<<dim3(NWG), dim3(NTHR), 0, stream>>>(
          x, Wih0, Whh0, bih0, bhh0, Whr0, Wihs, Whhs, bihs, bhhs, Whrs,
          out, yR, hR, WP, gI, cnt);
  } else {
    auto* kfn = lstm_kernel<false>;
    st = hipLaunchCooperativeKernel((void*)kfn, dim3(NWG), dim3(NTHR),
                                    args, 0, stream);
    if (st != hipSuccess)
      lstm_kernel<false><<<dim3(NWG), dim3(NTHR), 0, stream>>>(
          x, Wih0, Whh0, bih0, bhh0, Whr0, Wihs, Whhs, bihs, bhhs, Whrs,
          out, yR, hR, WP, gI, cnt);
  }
}